// Round 1
// baseline (737.903 us; speedup 1.0000x reference)
//
#include <hip/hip_runtime.h>
#include <math.h>

#define LS 65  // LDS row stride for 64x64 tiles (pad -> <=2-way bank conflicts)

constexpr int BATCH = 2, SEQ = 4096, DIM = 512, HEADS = 8, DH = 64, CH = 64;
constexpr int NC = SEQ / CH;        // 64 chunks per (b,h)
constexpr int BH = BATCH * HEADS;   // 16
constexpr int NCHUNK = BH * NC;     // 1024
constexpr int ROWS = BATCH * SEQ;   // 8192
constexpr int DI = HEADS * DH;      // 512

__device__ inline float sigmoidf_(float x){ return 1.f/(1.f+__expf(-x)); }
__device__ inline float dsilu_f(float x){ float s = sigmoidf_(x); return s*(1.f + x*(1.f-s)); }

// ---- block-wide sum over 256 threads ----
__device__ inline float block_sum256(float v, float* red, int tid){
  #pragma unroll
  for (int m = 1; m < 64; m <<= 1) v += __shfl_xor(v, m);
  if ((tid & 63) == 0) red[tid >> 6] = v;
  __syncthreads();
  return red[0] + red[1] + red[2] + red[3];
}

// =====================================================================
// K1: store-rmsnorm + retrieve-rmsnorm(shifted) + per-position lr
// grid = 8192 rows, 256 threads
// =====================================================================
__global__ __launch_bounds__(256) void k_store_norm(
    const float* __restrict__ seq, const float* __restrict__ wsn,
    const float* __restrict__ wrn, const float* __restrict__ wstep,
    float* __restrict__ s, float* __restrict__ rsh, float* __restrict__ lrp)
{
  __shared__ float srow[DIM];
  __shared__ float red[4];
  int row = blockIdx.x;
  int b = row >> 12, t = row & 4095;
  const float* x = seq + (size_t)row * DIM;
  int tid = threadIdx.x;
  float x0 = x[tid], x1 = x[tid + 256];
  float ss = block_sum256(x0*x0 + x1*x1, red, tid);
  float rinv = rsqrtf(ss / (float)DIM + 1e-6f);
  float s0 = x0 * rinv * wsn[tid], s1 = x1 * rinv * wsn[tid + 256];
  s[(size_t)row*DIM + tid] = s0;
  s[(size_t)row*DIM + tid + 256] = s1;
  srow[tid] = s0; srow[tid + 256] = s1;
  if (t >= CH){
    float* rr = rsh + ((size_t)b*SEQ + (t - CH)) * DIM;
    rr[tid]       = x0 * rinv * wrn[tid];
    rr[tid + 256] = x1 * rinv * wrn[tid + 256];
  }
  __syncthreads();
  // 8 groups of 32 lanes, group g computes dot(srow, w_step[:,g])
  int gh = tid >> 5, l = tid & 31;
  float acc = 0.f;
  for (int e = l; e < DIM; e += 32) acc += srow[e] * wstep[e*HEADS + gh];
  #pragma unroll
  for (int m = 1; m < 32; m <<= 1) acc += __shfl_xor(acc, m);
  if (l == 0){
    float sg = sigmoidf_(acc);
    lrp[(size_t)row*HEADS + gh] = __expf(-15.f * sg);
  }
}

// =====================================================================
// K3: chunk stats -> mom_gate, decay, lr (chunk mean)
// grid = BATCH*NC = 128 blocks
// =====================================================================
__global__ __launch_bounds__(256) void k_stats(
    const float* __restrict__ s, const float* __restrict__ lrp,
    const float* __restrict__ wmom, const float* __restrict__ wdec,
    float* __restrict__ mg, float* __restrict__ dec, float* __restrict__ lrc)
{
  __shared__ float smean[DIM];
  int blk = blockIdx.x;
  int b = blk >> 6, ch = blk & 63;
  int tid = threadIdx.x;
  const float* base = s + ((size_t)(b*SEQ + ch*CH)) * DIM;
  for (int e = tid; e < DIM; e += 256){
    float acc = 0.f;
    for (int i = 0; i < CH; i++) acc += base[(size_t)i*DIM + e];
    smean[e] = acc * (1.f/CH);
  }
  __syncthreads();
  int gh = tid >> 5, l = tid & 31;
  float am = 0.f, ad = 0.f;
  for (int e = l; e < DIM; e += 32){
    float v = smean[e];
    am += v * wmom[e*HEADS + gh];
    ad += v * wdec[e*HEADS + gh];
  }
  const float* lrbase = lrp + ((size_t)(b*SEQ + ch*CH)) * HEADS + gh;
  float al = lrbase[(size_t)l*HEADS] + lrbase[(size_t)(l+32)*HEADS];
  #pragma unroll
  for (int m = 1; m < 32; m <<= 1){
    am += __shfl_xor(am, m);
    ad += __shfl_xor(ad, m);
    al += __shfl_xor(al, m);
  }
  if (l == 0){
    int o = (b*HEADS + gh)*NC + ch;
    mg[o]  = sigmoidf_(am);
    dec[o] = sigmoidf_(ad);
    lrc[o] = al * (1.f/CH);
  }
}

// =====================================================================
// K2: generic f32 GEMM  C[MxN] = A[MxK] @ B[KxN]   (M%64==0,N%64==0,K%16==0)
// BM=BN=64, BK=16, 256 thr, 4x4 micro-tile
// =====================================================================
__global__ __launch_bounds__(256) void sgemm_kernel(
    const float* __restrict__ A, const float* __restrict__ B,
    float* __restrict__ C, int M, int N, int K)
{
  __shared__ float As[16][68];
  __shared__ float Bs[16][64];
  int tid = threadIdx.x;
  int tx = tid & 15, ty = tid >> 4;
  int n0 = blockIdx.x * 64, m0 = blockIdx.y * 64;
  float acc[4][4] = {};
  int la_m = tid >> 2;
  int la_k = (tid & 3) * 4;
  int lb_k = tid >> 4;
  int lb_n = (tid & 15) * 4;
  const float* Aptr = A + (size_t)(m0 + la_m) * K + la_k;
  const float* Bptr = B + (size_t)lb_k * N + n0 + lb_n;
  for (int k0 = 0; k0 < K; k0 += 16){
    float4 va = *(const float4*)(Aptr + k0);
    float4 vb = *(const float4*)(Bptr + (size_t)k0 * N);
    As[la_k+0][la_m] = va.x; As[la_k+1][la_m] = va.y;
    As[la_k+2][la_m] = va.z; As[la_k+3][la_m] = va.w;
    *(float4*)&Bs[lb_k][lb_n] = vb;
    __syncthreads();
    #pragma unroll
    for (int kk = 0; kk < 16; kk++){
      float4 a4 = *(const float4*)&As[kk][ty*4];
      float4 b4 = *(const float4*)&Bs[kk][tx*4];
      float a[4] = {a4.x, a4.y, a4.z, a4.w};
      float bb[4] = {b4.x, b4.y, b4.z, b4.w};
      #pragma unroll
      for (int r = 0; r < 4; r++)
        #pragma unroll
        for (int c = 0; c < 4; c++) acc[r][c] = fmaf(a[r], bb[c], acc[r][c]);
    }
    __syncthreads();
  }
  #pragma unroll
  for (int r = 0; r < 4; r++){
    float4 o = make_float4(acc[r][0], acc[r][1], acc[r][2], acc[r][3]);
    *(float4*)(C + (size_t)(m0 + ty*4 + r) * N + n0 + tx*4) = o;
  }
}

// ---- 64x64 LDS GEMM helper: C = alpha * op(A) @ op(B) ----
template<bool TA, bool TB, bool SILUA>
__device__ inline void gemm64_acc(const float* __restrict__ A, const float* __restrict__ B,
                                  float (&acc)[4][4], int tx, int ty, float alpha)
{
  #pragma unroll
  for (int r = 0; r < 4; r++)
    #pragma unroll
    for (int c = 0; c < 4; c++) acc[r][c] = 0.f;
  #pragma unroll 4
  for (int k = 0; k < 64; k++){
    float a[4], b[4];
    #pragma unroll
    for (int r = 0; r < 4; r++){
      int i = ty*4 + r;
      float v = TA ? A[k*LS + i] : A[i*LS + k];
      if constexpr (SILUA) v = v * sigmoidf_(v);
      a[r] = v;
    }
    #pragma unroll
    for (int c = 0; c < 4; c++){
      int j = tx*4 + c;
      b[c] = TB ? B[j*LS + k] : B[k*LS + j];
    }
    #pragma unroll
    for (int r = 0; r < 4; r++)
      #pragma unroll
      for (int c = 0; c < 4; c++) acc[r][c] = fmaf(a[r], b[c], acc[r][c]);
  }
  if (alpha != 1.f){
    #pragma unroll
    for (int r = 0; r < 4; r++)
      #pragma unroll
      for (int c = 0; c < 4; c++) acc[r][c] *= alpha;
  }
}

__device__ inline void store_acc64(float* C, const float (&acc)[4][4], int tx, int ty){
  #pragma unroll
  for (int r = 0; r < 4; r++)
    #pragma unroll
    for (int c = 0; c < 4; c++) C[(ty*4+r)*LS + tx*4 + c] = acc[r][c];
}

__device__ inline void store_grad64(float* g, const float (&acc)[4][4], float scale, int tx, int ty){
  #pragma unroll
  for (int r = 0; r < 4; r++){
    float4 o = make_float4(acc[r][0]*scale, acc[r][1]*scale, acc[r][2]*scale, acc[r][3]*scale);
    *(float4*)(g + (ty*4+r)*64 + tx*4) = o;
  }
}

__device__ inline void load64(float* dst, const float* __restrict__ src, int srcStride, int tid){
  #pragma unroll
  for (int rr = 0; rr < 16; rr++){
    int idx = rr*256 + tid;
    int i = idx >> 6, j = idx & 63;
    dst[i*LS + j] = src[(size_t)i*srcStride + j];
  }
}

// causal softmax over rows of 64x64 LDS matrix; 4 threads/row
__device__ inline void softmax_causal64(float* A, int tid){
  int row = tid >> 2, q = tid & 3;
  float v[16];
  #pragma unroll
  for (int c = 0; c < 16; c++){
    int col = q*16 + c;
    float x = A[row*LS + col];
    v[c] = (col <= row) ? x : -1e9f;
  }
  float m = v[0];
  #pragma unroll
  for (int c = 1; c < 16; c++) m = fmaxf(m, v[c]);
  m = fmaxf(m, __shfl_xor(m, 1));
  m = fmaxf(m, __shfl_xor(m, 2));
  float ssum = 0.f;
  #pragma unroll
  for (int c = 0; c < 16; c++){ v[c] = __expf(v[c] - m); ssum += v[c]; }
  ssum += __shfl_xor(ssum, 1);
  ssum += __shfl_xor(ssum, 2);
  float inv = 1.f / ssum;
  #pragma unroll
  for (int c = 0; c < 16; c++) A[row*LS + q*16 + c] = v[c] * inv;
}

// softmax backward: D = A * (D - rowsum(D*A)) in place
__device__ inline void softmax_bwd64(float* D, const float* A, int tid){
  int row = tid >> 2, q = tid & 3;
  float d[16], a[16], rs = 0.f;
  #pragma unroll
  for (int c = 0; c < 16; c++){
    d[c] = D[row*LS + q*16 + c];
    a[c] = A[row*LS + q*16 + c];
    rs += d[c]*a[c];
  }
  rs += __shfl_xor(rs, 1);
  rs += __shfl_xor(rs, 2);
  #pragma unroll
  for (int c = 0; c < 16; c++) D[row*LS + q*16 + c] = a[c]*(d[c] - rs);
}

// =====================================================================
// K4: per-chunk attention fwd+bwd -> surprise = -lr * grad  (4 matrices)
// grid = 1024 chunks, 256 threads, ~130KB LDS
// =====================================================================
__global__ __launch_bounds__(256, 1) void k_grads(
    const float* __restrict__ kv,
    const float* __restrict__ wq, const float* __restrict__ wk,
    const float* __restrict__ wv1, const float* __restrict__ wv2,
    const float* __restrict__ lrc, float* __restrict__ g)
{
  __shared__ float sm[8 * 64 * LS];
  float *X = sm, *W = sm + 64*LS, *Q = sm + 2*64*LS, *Kb = sm + 3*64*LS,
        *V = sm + 4*64*LS, *Ab = sm + 5*64*LS, *H = sm + 6*64*LS, *T2 = sm + 7*64*LS;
  int chunk = blockIdx.x;
  int bh = chunk >> 6, t = chunk & 63;
  int b = bh >> 3, h = bh & 7;
  int tid = threadIdx.x, tx = tid & 15, ty = tid >> 4;
  const float* xbase = kv + ((size_t)(b*SEQ + t*CH)) * (2*DI) + h*DH;
  const float* tbase = xbase + DI;   // values half
  float negLr = -lrc[bh*NC + t];
  float acc[4][4];

  load64(X, xbase, 2*DI, tid);
  load64(W, wq, 64, tid);
  __syncthreads();
  gemm64_acc<false,false,false>(X, W, acc, tx, ty, 1.f);
  store_acc64(Q, acc, tx, ty); __syncthreads();
  load64(W, wk, 64, tid); __syncthreads();
  gemm64_acc<false,false,false>(X, W, acc, tx, ty, 1.f);
  store_acc64(Kb, acc, tx, ty); __syncthreads();
  load64(W, wv1, 64, tid); __syncthreads();
  gemm64_acc<false,false,false>(X, W, acc, tx, ty, 1.f);
  store_acc64(V, acc, tx, ty); __syncthreads();
  // dots = Q K^T / 8
  gemm64_acc<false,true,false>(Q, Kb, acc, tx, ty, 0.125f);
  store_acc64(Ab, acc, tx, ty); __syncthreads();
  softmax_causal64(Ab, tid); __syncthreads();
  // H = A V
  gemm64_acc<false,false,false>(Ab, V, acc, tx, ty, 1.f);
  store_acc64(H, acc, tx, ty); __syncthreads();
  load64(W, wv2, 64, tid); __syncthreads();
  // pred = silu(H) @ Wv2 ; T2 = dpred = (2/64)(pred - tgt)
  gemm64_acc<false,false,true>(H, W, acc, tx, ty, 1.f);
  #pragma unroll
  for (int r = 0; r < 4; r++)
    #pragma unroll
    for (int c = 0; c < 4; c++){
      int i = ty*4 + r, j = tx*4 + c;
      T2[i*LS + j] = (acc[r][c] - tbase[(size_t)i*(2*DI) + j]) * (2.f/64.f);
    }
  __syncthreads();
  // dWv2 = silu(H)^T @ T2
  gemm64_acc<true,false,true>(H, T2, acc, tx, ty, 1.f);
  store_grad64(g + ((size_t)(3*NCHUNK + chunk))*4096, acc, negLr, tx, ty);
  __syncthreads();
  // dHd = (T2 @ Wv2^T) * silu'(H)   (in place into H)
  gemm64_acc<false,true,false>(T2, W, acc, tx, ty, 1.f);
  #pragma unroll
  for (int r = 0; r < 4; r++)
    #pragma unroll
    for (int c = 0; c < 4; c++){
      int i = ty*4 + r, j = tx*4 + c;
      H[i*LS + j] = acc[r][c] * dsilu_f(H[i*LS + j]);
    }
  __syncthreads();
  // dA = dHd @ V^T
  gemm64_acc<false,true,false>(H, V, acc, tx, ty, 1.f);
  store_acc64(T2, acc, tx, ty); __syncthreads();
  // dv = A^T @ dHd
  gemm64_acc<true,false,false>(Ab, H, acc, tx, ty, 1.f);
  store_acc64(W, acc, tx, ty); __syncthreads();
  // dWv1 = X^T @ dv
  gemm64_acc<true,false,false>(X, W, acc, tx, ty, 1.f);
  store_grad64(g + ((size_t)(2*NCHUNK + chunk))*4096, acc, negLr, tx, ty);
  __syncthreads();
  // softmax backward on T2 (ddots, unscaled)
  softmax_bwd64(T2, Ab, tid); __syncthreads();
  // dq = ddots @ K / 8
  gemm64_acc<false,false,false>(T2, Kb, acc, tx, ty, 0.125f);
  store_acc64(W, acc, tx, ty); __syncthreads();
  gemm64_acc<true,false,false>(X, W, acc, tx, ty, 1.f);
  store_grad64(g + ((size_t)(0*NCHUNK + chunk))*4096, acc, negLr, tx, ty);
  __syncthreads();
  // dk = ddots^T @ Q / 8
  gemm64_acc<true,false,false>(T2, Q, acc, tx, ty, 0.125f);
  store_acc64(W, acc, tx, ty); __syncthreads();
  gemm64_acc<true,false,false>(X, W, acc, tx, ty, 1.f);
  store_grad64(g + ((size_t)(1*NCHUNK + chunk))*4096, acc, negLr, tx, ty);
}

// =====================================================================
// K5: double associative scan over chunks; in-place g -> per-chunk weights
// total threads = 4 * 16 * 4096 = 262144
// =====================================================================
__global__ __launch_bounds__(256) void k_scan(
    float* __restrict__ g, const float* __restrict__ mg, const float* __restrict__ dec,
    const float* __restrict__ wq, const float* __restrict__ wk,
    const float* __restrict__ wv1, const float* __restrict__ wv2)
{
  int idx = blockIdx.x * 256 + threadIdx.x;
  int e = idx & 4095;
  int bh = (idx >> 12) & 15;
  int name = idx >> 16;
  const float* past = (name == 0) ? wq : (name == 1) ? wk : (name == 2) ? wv1 : wv2;
  float base = past[e];
  float m = 0.f, u = 0.f;
  for (int t = 0; t < NC; t++){
    size_t off = ((size_t)(name*NCHUNK + bh*NC + t)) * 4096 + e;
    float su = g[off];
    float gm = mg[bh*NC + t];
    float dc = dec[bh*NC + t];
    m = gm * m + su;
    u = (1.f - dc) * u + m;
    g[off] = base + u;
  }
}

// =====================================================================
// K6: retrieval attention with per-chunk weights
// grid = 1024 chunks, 256 threads, ~114KB LDS
// =====================================================================
__global__ __launch_bounds__(256, 1) void k_retrieve(
    const float* __restrict__ qb, const float* __restrict__ Wg, float* __restrict__ vals)
{
  __shared__ float sm[7 * 64 * LS];
  float *X = sm, *W = sm + 64*LS, *Q = sm + 2*64*LS, *Kb = sm + 3*64*LS,
        *V = sm + 4*64*LS, *Ab = sm + 5*64*LS, *H = sm + 6*64*LS;
  int chunk = blockIdx.x;
  int bh = chunk >> 6, t = chunk & 63;
  int b = bh >> 3, h = bh & 7;
  int tid = threadIdx.x, tx = tid & 15, ty = tid >> 4;
  const float* xb = qb + ((size_t)(b*SEQ + t*CH)) * DI + h*DH;
  float acc[4][4];

  load64(X, xb, DI, tid);
  load64(W, Wg + ((size_t)(0*NCHUNK + chunk))*4096, 64, tid);
  __syncthreads();
  gemm64_acc<false,false,false>(X, W, acc, tx, ty, 1.f);
  store_acc64(Q, acc, tx, ty); __syncthreads();
  load64(W, Wg + ((size_t)(1*NCHUNK + chunk))*4096, 64, tid); __syncthreads();
  gemm64_acc<false,false,false>(X, W, acc, tx, ty, 1.f);
  store_acc64(Kb, acc, tx, ty); __syncthreads();
  load64(W, Wg + ((size_t)(2*NCHUNK + chunk))*4096, 64, tid); __syncthreads();
  gemm64_acc<false,false,false>(X, W, acc, tx, ty, 1.f);
  store_acc64(V, acc, tx, ty); __syncthreads();
  gemm64_acc<false,true,false>(Q, Kb, acc, tx, ty, 0.125f);
  store_acc64(Ab, acc, tx, ty); __syncthreads();
  softmax_causal64(Ab, tid); __syncthreads();
  gemm64_acc<false,false,false>(Ab, V, acc, tx, ty, 1.f);
  store_acc64(H, acc, tx, ty); __syncthreads();
  load64(W, Wg + ((size_t)(3*NCHUNK + chunk))*4096, 64, tid); __syncthreads();
  gemm64_acc<false,false,true>(H, W, acc, tx, ty, 1.f);
  // write vals[b][t*64+i][h*64+j]
  #pragma unroll
  for (int r = 0; r < 4; r++){
    float4 o = make_float4(acc[r][0], acc[r][1], acc[r][2], acc[r][3]);
    *(float4*)(vals + ((size_t)(b*SEQ + t*CH + ty*4 + r))*DI + h*DH + tx*4) = o;
  }
}

// =====================================================================
// K8: final rmsnorm + shift: out[b][r+64] = rmsnorm(tmp[b][r]) * w_post
// grid = BATCH * 4032 rows
// =====================================================================
__global__ __launch_bounds__(256) void k_outnorm(
    const float* __restrict__ tmp, const float* __restrict__ wpn, float* __restrict__ out)
{
  __shared__ float red[4];
  int row = blockIdx.x;
  int b = row / (SEQ - CH), r = row % (SEQ - CH);
  const float* src = tmp + ((size_t)b*SEQ + r) * DIM;
  float* dst = out + ((size_t)b*SEQ + r + CH) * DIM;
  int tid = threadIdx.x;
  float x0 = src[tid], x1 = src[tid + 256];
  float ss = block_sum256(x0*x0 + x1*x1, red, tid);
  float rinv = rsqrtf(ss / (float)DIM + 1e-6f);
  dst[tid]       = x0 * rinv * wpn[tid];
  dst[tid + 256] = x1 * rinv * wpn[tid + 256];
}

// =====================================================================
extern "C" void kernel_launch(void* const* d_in, const int* in_sizes, int n_in,
                              void* d_out, int out_size, void* d_ws, size_t ws_size,
                              hipStream_t stream)
{
  (void)in_sizes; (void)n_in; (void)ws_size;
  const float* seq   = (const float*)d_in[0];
  const float* wsn   = (const float*)d_in[1];
  const float* wrn   = (const float*)d_in[2];
  const float* wpn   = (const float*)d_in[3];
  const float* w_q   = (const float*)d_in[4];
  const float* w_kv  = (const float*)d_in[5];
  const float* wstep = (const float*)d_in[6];
  const float* wmom  = (const float*)d_in[7];
  const float* wdec  = (const float*)d_in[8];
  const float* wcomb = (const float*)d_in[9];
  const float* wq    = (const float*)d_in[10];
  const float* wk    = (const float*)d_in[11];
  const float* wv1   = (const float*)d_in[12];
  const float* wv2   = (const float*)d_in[13];
  float* out = (float*)d_out;

  float* ws  = (float*)d_ws;
  float* s    = ws;                      // 8192*512           (also vals)
  float* rsh  = s + (size_t)ROWS*DIM;    // 8192*512           (also tmp)
  float* kv   = rsh + (size_t)ROWS*DIM;  // 8192*1024
  float* qb   = kv + (size_t)ROWS*2*DI;  // 8192*512
  float* g    = qb + (size_t)ROWS*DI;    // 4*1024*4096
  float* lrp  = g + (size_t)4*NCHUNK*4096; // 8192*8
  float* mg   = lrp + (size_t)ROWS*HEADS;  // 1024
  float* dec  = mg + BH*NC;
  float* lrc  = dec + BH*NC;
  float* vals = s;
  float* tmp  = rsh;

  // zero: output rows [0,64), and rsh pad rows [4032,4096) per batch
  hipMemsetAsync(d_out, 0, (size_t)out_size * sizeof(float), stream);
  for (int b = 0; b < BATCH; b++)
    hipMemsetAsync(rsh + ((size_t)b*SEQ + (SEQ - CH))*DIM, 0,
                   (size_t)CH*DIM*sizeof(float), stream);

  k_store_norm<<<ROWS, 256, 0, stream>>>(seq, wsn, wrn, wstep, s, rsh, lrp);
  sgemm_kernel<<<dim3((2*DI)/64, ROWS/64), 256, 0, stream>>>(s, w_kv, kv, ROWS, 2*DI, DIM);
  k_stats<<<BATCH*NC, 256, 0, stream>>>(s, lrp, wmom, wdec, mg, dec, lrc);
  sgemm_kernel<<<dim3(DI/64, ROWS/64), 256, 0, stream>>>(rsh, w_q, qb, ROWS, DI, DIM);
  k_grads<<<NCHUNK, 256, 0, stream>>>(kv, wq, wk, wv1, wv2, lrc, g);
  k_scan<<<(4*BH*4096)/256, 256, 0, stream>>>(g, mg, dec, wq, wk, wv1, wv2);
  k_retrieve<<<NCHUNK, 256, 0, stream>>>(qb, g, vals);
  sgemm_kernel<<<dim3(DIM/64, ROWS/64), 256, 0, stream>>>(vals, wcomb, tmp, ROWS, DIM, DIM);
  k_outnorm<<<BATCH*(SEQ - CH), 256, 0, stream>>>(tmp, wpn, out);
}

// Round 2
// 448.367 us; speedup vs baseline: 1.6458x; 1.6458x over previous
//
#include <hip/hip_runtime.h>
#include <math.h>

constexpr int BATCH = 2, SEQ = 4096, DIM = 512, HEADS = 8, DH = 64, CH = 64;
constexpr int NC = SEQ / CH;        // 64 chunks per (b,h)
constexpr int BH = BATCH * HEADS;   // 16
constexpr int NCHUNK = BH * NC;     // 1024
constexpr int ROWS = BATCH * SEQ;   // 8192
constexpr int DI = HEADS * DH;      // 512
constexpr int TS = 64 * 72;         // bf16 tile: 64 rows, stride 72 elems (144B rows, 16B-aligned frags)

typedef __attribute__((ext_vector_type(8))) short short8;
typedef __attribute__((ext_vector_type(4))) short short4v;
typedef __attribute__((ext_vector_type(4))) float f32x4;

__device__ inline float sigmoidf_(float x){ return 1.f/(1.f+__expf(-x)); }
__device__ inline float dsilu_f(float x){ float s = sigmoidf_(x); return s*(1.f + x*(1.f-s)); }

__device__ inline unsigned short f2b(float f){
  union { float f; unsigned int u; } c; c.f = f;
  unsigned int u = c.u;
  unsigned int r = (u + 0x7FFFu + ((u >> 16) & 1u)) >> 16;
  return (unsigned short)r;
}
__device__ inline float b2f(unsigned short h){
  union { unsigned int u; float f; } c; c.u = ((unsigned int)h) << 16;
  return c.f;
}

// ---- block-wide sum over 256 threads ----
__device__ inline float block_sum256(float v, float* red, int tid){
  #pragma unroll
  for (int m = 1; m < 64; m <<= 1) v += __shfl_xor(v, m);
  if ((tid & 63) == 0) red[tid >> 6] = v;
  __syncthreads();
  return red[0] + red[1] + red[2] + red[3];
}

// =====================================================================
// MFMA 64x64 building blocks (4 waves, each wave owns a 32x32 quadrant
// split as 2x2 16x16 tiles; K=64 in two K=32 steps)
// A-tile: M x K row-major bf16 (k contiguous), stride 72
// B-tile: N x K row-major bf16 (k contiguous)  i.e. B^T, stride 72
// computes C = A * B^T(tile-layout)  == mathematical A(64xK) @ B'(Kx64)
// =====================================================================
struct MM { int lr, lg, rowbase, colbase; };
__device__ inline MM mmctx(){
  int tid = threadIdx.x;
  int wid = tid >> 6, lane = tid & 63;
  MM m; m.lr = lane & 15; m.lg = lane >> 4;
  m.rowbase = (wid >> 1) * 32; m.colbase = (wid & 1) * 32;
  return m;
}

template<bool SILUA>
__device__ inline void mm64(const unsigned short* A, const unsigned short* B,
                            f32x4 (&acc)[2][2], const MM& m)
{
  #pragma unroll
  for (int rt = 0; rt < 2; rt++)
    #pragma unroll
    for (int ct = 0; ct < 2; ct++) acc[rt][ct] = (f32x4){0.f, 0.f, 0.f, 0.f};
  #pragma unroll
  for (int ks = 0; ks < 2; ks++){
    short8 a[2], b[2];
    #pragma unroll
    for (int rt = 0; rt < 2; rt++){
      a[rt] = *(const short8*)&A[(m.rowbase + rt*16 + m.lr)*72 + ks*32 + m.lg*8];
      if constexpr (SILUA){
        #pragma unroll
        for (int j = 0; j < 8; j++){
          float v = b2f((unsigned short)a[rt][j]);
          v = v * sigmoidf_(v);
          a[rt][j] = (short)f2b(v);
        }
      }
    }
    #pragma unroll
    for (int ct = 0; ct < 2; ct++)
      b[ct] = *(const short8*)&B[(m.colbase + ct*16 + m.lr)*72 + ks*32 + m.lg*8];
    #pragma unroll
    for (int rt = 0; rt < 2; rt++)
      #pragma unroll
      for (int ct = 0; ct < 2; ct++)
        acc[rt][ct] = __builtin_amdgcn_mfma_f32_16x16x32_bf16(a[rt], b[ct], acc[rt][ct], 0, 0, 0);
  }
}

// store C row-major bf16 (stride 72)
__device__ inline void storeN64(unsigned short* R, const f32x4 (&acc)[2][2], const MM& m, float scale){
  #pragma unroll
  for (int rt = 0; rt < 2; rt++)
    #pragma unroll
    for (int ct = 0; ct < 2; ct++){
      int c  = m.colbase + ct*16 + m.lr;
      int mb = m.rowbase + rt*16 + m.lg*4;
      #pragma unroll
      for (int r = 0; r < 4; r++) R[(mb+r)*72 + c] = f2b(acc[rt][ct][r] * scale);
    }
}
// store C transposed bf16 (T[n][m], stride 72) — 8B vector writes
__device__ inline void storeT64(unsigned short* T, const f32x4 (&acc)[2][2], const MM& m, float scale){
  #pragma unroll
  for (int rt = 0; rt < 2; rt++)
    #pragma unroll
    for (int ct = 0; ct < 2; ct++){
      int c  = m.colbase + ct*16 + m.lr;
      int mb = m.rowbase + rt*16 + m.lg*4;
      short4v p;
      #pragma unroll
      for (int r = 0; r < 4; r++) p[r] = (short)f2b(acc[rt][ct][r] * scale);
      *(short4v*)&T[c*72 + mb] = p;
    }
}
// store C f32 into score scratch (stride 66)
__device__ inline void storeSC(float* S, const f32x4 (&acc)[2][2], const MM& m, float scale){
  #pragma unroll
  for (int rt = 0; rt < 2; rt++)
    #pragma unroll
    for (int ct = 0; ct < 2; ct++){
      int c  = m.colbase + ct*16 + m.lr;
      int mb = m.rowbase + rt*16 + m.lg*4;
      #pragma unroll
      for (int r = 0; r < 4; r++) S[(mb+r)*66 + c] = acc[rt][ct][r] * scale;
    }
}
// store C f32 to global 64x64 row-major
__device__ inline void storeG64(float* __restrict__ G, const f32x4 (&acc)[2][2], const MM& m, float scale){
  #pragma unroll
  for (int rt = 0; rt < 2; rt++)
    #pragma unroll
    for (int ct = 0; ct < 2; ct++){
      int c  = m.colbase + ct*16 + m.lr;
      int mb = m.rowbase + rt*16 + m.lg*4;
      #pragma unroll
      for (int r = 0; r < 4; r++) G[(mb+r)*64 + c] = acc[rt][ct][r] * scale;
    }
}

// load a 64x64 f32 global tile into bf16 LDS, row-major and/or transposed
template<bool DOR, bool DOT>
__device__ inline void loadTile(unsigned short* R, unsigned short* T,
                                const float* __restrict__ src, int stride, int tid){
  #pragma unroll
  for (int it = 0; it < 16; it++){
    int idx = it*256 + tid;
    int i = idx >> 6, j = idx & 63;
    unsigned short h = f2b(src[(size_t)i*stride + j]);
    if constexpr (DOR) R[i*72 + j] = h;
    if constexpr (DOT) T[j*72 + i] = h;
  }
}

// =====================================================================
// K1: store-rmsnorm + retrieve-rmsnorm(shifted) + per-position lr
// =====================================================================
__global__ __launch_bounds__(256) void k_store_norm(
    const float* __restrict__ seq, const float* __restrict__ wsn,
    const float* __restrict__ wrn, const float* __restrict__ wstep,
    float* __restrict__ s, float* __restrict__ rsh, float* __restrict__ lrp)
{
  __shared__ float srow[DIM];
  __shared__ float red[4];
  int row = blockIdx.x;
  int b = row >> 12, t = row & 4095;
  const float* x = seq + (size_t)row * DIM;
  int tid = threadIdx.x;
  float x0 = x[tid], x1 = x[tid + 256];
  float ss = block_sum256(x0*x0 + x1*x1, red, tid);
  float rinv = rsqrtf(ss / (float)DIM + 1e-6f);
  float s0 = x0 * rinv * wsn[tid], s1 = x1 * rinv * wsn[tid + 256];
  s[(size_t)row*DIM + tid] = s0;
  s[(size_t)row*DIM + tid + 256] = s1;
  srow[tid] = s0; srow[tid + 256] = s1;
  if (t >= CH){
    float* rr = rsh + ((size_t)b*SEQ + (t - CH)) * DIM;
    rr[tid]       = x0 * rinv * wrn[tid];
    rr[tid + 256] = x1 * rinv * wrn[tid + 256];
  }
  __syncthreads();
  int gh = tid >> 5, l = tid & 31;
  float acc = 0.f;
  for (int e = l; e < DIM; e += 32) acc += srow[e] * wstep[e*HEADS + gh];
  #pragma unroll
  for (int m = 1; m < 32; m <<= 1) acc += __shfl_xor(acc, m);
  if (l == 0){
    float sg = sigmoidf_(acc);
    lrp[(size_t)row*HEADS + gh] = __expf(-15.f * sg);
  }
}

// =====================================================================
// K3: chunk stats -> mom_gate, decay, lr (chunk mean)
// =====================================================================
__global__ __launch_bounds__(256) void k_stats(
    const float* __restrict__ s, const float* __restrict__ lrp,
    const float* __restrict__ wmom, const float* __restrict__ wdec,
    float* __restrict__ mg, float* __restrict__ dec, float* __restrict__ lrc)
{
  __shared__ float smean[DIM];
  int blk = blockIdx.x;
  int b = blk >> 6, ch = blk & 63;
  int tid = threadIdx.x;
  const float* base = s + ((size_t)(b*SEQ + ch*CH)) * DIM;
  for (int e = tid; e < DIM; e += 256){
    float acc = 0.f;
    for (int i = 0; i < CH; i++) acc += base[(size_t)i*DIM + e];
    smean[e] = acc * (1.f/CH);
  }
  __syncthreads();
  int gh = tid >> 5, l = tid & 31;
  float am = 0.f, ad = 0.f;
  for (int e = l; e < DIM; e += 32){
    float v = smean[e];
    am += v * wmom[e*HEADS + gh];
    ad += v * wdec[e*HEADS + gh];
  }
  const float* lrbase = lrp + ((size_t)(b*SEQ + ch*CH)) * HEADS + gh;
  float al = lrbase[(size_t)l*HEADS] + lrbase[(size_t)(l+32)*HEADS];
  #pragma unroll
  for (int m = 1; m < 32; m <<= 1){
    am += __shfl_xor(am, m);
    ad += __shfl_xor(ad, m);
    al += __shfl_xor(al, m);
  }
  if (l == 0){
    int o = (b*HEADS + gh)*NC + ch;
    mg[o]  = sigmoidf_(am);
    dec[o] = sigmoidf_(ad);
    lrc[o] = al * (1.f/CH);
  }
}

// =====================================================================
// K2: generic f32 GEMM  C[MxN] = A[MxK] @ B[KxN]
// =====================================================================
__global__ __launch_bounds__(256) void sgemm_kernel(
    const float* __restrict__ A, const float* __restrict__ B,
    float* __restrict__ C, int M, int N, int K)
{
  __shared__ float As[16][68];
  __shared__ float Bs[16][64];
  int tid = threadIdx.x;
  int tx = tid & 15, ty = tid >> 4;
  int n0 = blockIdx.x * 64, m0 = blockIdx.y * 64;
  float acc[4][4] = {};
  int la_m = tid >> 2;
  int la_k = (tid & 3) * 4;
  int lb_k = tid >> 4;
  int lb_n = (tid & 15) * 4;
  const float* Aptr = A + (size_t)(m0 + la_m) * K + la_k;
  const float* Bptr = B + (size_t)lb_k * N + n0 + lb_n;
  for (int k0 = 0; k0 < K; k0 += 16){
    float4 va = *(const float4*)(Aptr + k0);
    float4 vb = *(const float4*)(Bptr + (size_t)k0 * N);
    As[la_k+0][la_m] = va.x; As[la_k+1][la_m] = va.y;
    As[la_k+2][la_m] = va.z; As[la_k+3][la_m] = va.w;
    *(float4*)&Bs[lb_k][lb_n] = vb;
    __syncthreads();
    #pragma unroll
    for (int kk = 0; kk < 16; kk++){
      float4 a4 = *(const float4*)&As[kk][ty*4];
      float4 b4 = *(const float4*)&Bs[kk][tx*4];
      float a[4] = {a4.x, a4.y, a4.z, a4.w};
      float bb[4] = {b4.x, b4.y, b4.z, b4.w};
      #pragma unroll
      for (int r = 0; r < 4; r++)
        #pragma unroll
        for (int c = 0; c < 4; c++) acc[r][c] = fmaf(a[r], bb[c], acc[r][c]);
    }
    __syncthreads();
  }
  #pragma unroll
  for (int r = 0; r < 4; r++){
    float4 o = make_float4(acc[r][0], acc[r][1], acc[r][2], acc[r][3]);
    *(float4*)(C + (size_t)(m0 + ty*4 + r) * N + n0 + tx*4) = o;
  }
}

// =====================================================================
// K4: per-chunk attention fwd+bwd -> surprise = -lr * grad  (MFMA bf16)
// grid = 1024 chunks, 256 threads (4 waves), ~127KB LDS
// =====================================================================
__global__ __launch_bounds__(256, 1) void k_grads(
    const float* __restrict__ kv,
    const float* __restrict__ wq, const float* __restrict__ wk,
    const float* __restrict__ wv1, const float* __restrict__ wv2,
    const float* __restrict__ lrc, float* __restrict__ g)
{
  __shared__ __align__(16) unsigned short sm[12*TS];
  __shared__ __align__(16) float SC[64*66];
  unsigned short *Xr = sm,        *XT = sm + TS,
                 *s2 = sm + 2*TS, *s3 = sm + 3*TS, *s4 = sm + 4*TS,
                 *s5 = sm + 5*TS, *s6 = sm + 6*TS, *s7 = sm + 7*TS,
                 *s8 = sm + 8*TS, *s9 = sm + 9*TS, *s10 = sm + 10*TS,
                 *s11 = sm + 11*TS;
  // slot plan:
  // Xr : X       -> T2row -> dA -> dvT -> dqT -> dkT
  // XT : X^T (live to end)
  // s2 : WqT -> VT -> T2T -> dHdrow
  // s3 : WkT -> rawH -> T3row
  // s4 : Wv1T -> rawHT -> dHdT
  // s5 : Wv2T
  // s6 : Wv2row -> T3T
  // s7 : Qrow -> Arow
  // s8 : QT (live to end)
  // s9 : Krow -> AT
  // s10: KT
  // s11: Vrow
  int chunk = blockIdx.x;
  int bh = chunk >> 6, t = chunk & 63;
  int b = bh >> 3, h = bh & 7;
  int tid = threadIdx.x;
  MM M = mmctx();
  const float* xbase = kv + ((size_t)(b*SEQ + t*CH)) * (2*DI) + h*DH;
  const float* tbase = xbase + DI;   // values half
  float negLr = -lrc[bh*NC + t];
  f32x4 acc[2][2];

  // P0: loads
  loadTile<true,true>(Xr, XT, xbase, 2*DI, tid);
  loadTile<false,true>(nullptr, s2, wq, 64, tid);
  loadTile<false,true>(nullptr, s3, wk, 64, tid);
  loadTile<false,true>(nullptr, s4, wv1, 64, tid);
  loadTile<true,true>(s6, s5, wv2, 64, tid);
  __syncthreads();
  // P1: Q = X @ Wq
  mm64<false>(Xr, s2, acc, M);
  storeN64(s7, acc, M, 1.f); storeT64(s8, acc, M, 1.f);
  __syncthreads();
  // P2: K = X @ Wk
  mm64<false>(Xr, s3, acc, M);
  storeN64(s9, acc, M, 1.f); storeT64(s10, acc, M, 1.f);
  __syncthreads();
  // P3: V = X @ Wv1
  mm64<false>(Xr, s4, acc, M);
  storeN64(s11, acc, M, 1.f); storeT64(s2, acc, M, 1.f);   // VT -> s2
  __syncthreads();
  // P4: S = Q K^T / 8
  mm64<false>(s7, s9, acc, M);
  storeSC(SC, acc, M, 0.125f);
  __syncthreads();
  // P5: causal softmax -> Arow(s7), AT(s9)
  {
    int row = tid >> 2, q = tid & 3;
    float p[16];
    float mx = -1e30f;
    #pragma unroll
    for (int cc = 0; cc < 16; cc++){
      int col = q*16 + cc;
      float x = SC[row*66 + col];
      p[cc] = (col <= row) ? x : -1e9f;
      mx = fmaxf(mx, p[cc]);
    }
    mx = fmaxf(mx, __shfl_xor(mx, 1));
    mx = fmaxf(mx, __shfl_xor(mx, 2));
    float sum = 0.f;
    #pragma unroll
    for (int cc = 0; cc < 16; cc++){ p[cc] = __expf(p[cc] - mx); sum += p[cc]; }
    sum += __shfl_xor(sum, 1);
    sum += __shfl_xor(sum, 2);
    float inv = 1.f / sum;
    #pragma unroll
    for (int cc = 0; cc < 16; cc++){
      int col = q*16 + cc;
      unsigned short hh = f2b(p[cc] * inv);
      s7[row*72 + col] = hh;
      s9[col*72 + row] = hh;
    }
  }
  __syncthreads();
  // P6: H = A @ V  -> rawH(s3), rawHT(s4)
  mm64<false>(s7, s2, acc, M);
  storeN64(s3, acc, M, 1.f); storeT64(s4, acc, M, 1.f);
  __syncthreads();
  // P7: pred = silu(H) @ Wv2 ; T2 = (pred - tgt)*(2/64) -> T2row(Xr), T2T(s2)
  mm64<true>(s3, s5, acc, M);
  #pragma unroll
  for (int rt = 0; rt < 2; rt++)
    #pragma unroll
    for (int ct = 0; ct < 2; ct++){
      int c  = M.colbase + ct*16 + M.lr;
      int mb = M.rowbase + rt*16 + M.lg*4;
      #pragma unroll
      for (int r = 0; r < 4; r++){
        float t2 = (acc[rt][ct][r] - tbase[(size_t)(mb+r)*(2*DI) + c]) * (2.f/64.f);
        unsigned short hh = f2b(t2);
        Xr[(mb+r)*72 + c] = hh;
        s2[c*72 + (mb+r)] = hh;
      }
    }
  __syncthreads();
  // P8: dWv2 = silu(H)^T @ T2  -> global
  mm64<true>(s4, s2, acc, M);
  storeG64(g + ((size_t)(3*NCHUNK + chunk))*4096, acc, M, negLr);
  __syncthreads();
  // P9: dHd = (T2 @ Wv2^T) * dsilu(rawH) -> dHdrow(s2), dHdT(s4)
  mm64<false>(Xr, s6, acc, M);
  #pragma unroll
  for (int rt = 0; rt < 2; rt++)
    #pragma unroll
    for (int ct = 0; ct < 2; ct++){
      int c  = M.colbase + ct*16 + M.lr;
      int mb = M.rowbase + rt*16 + M.lg*4;
      #pragma unroll
      for (int r = 0; r < 4; r++){
        float x = b2f(s3[(mb+r)*72 + c]);
        float d = acc[rt][ct][r] * dsilu_f(x);
        unsigned short hh = f2b(d);
        s2[(mb+r)*72 + c] = hh;
        s4[c*72 + (mb+r)] = hh;
      }
    }
  __syncthreads();
  // P10: dA = dHd @ V^T -> bf16 row (Xr)
  mm64<false>(s2, s11, acc, M);
  storeN64(Xr, acc, M, 1.f);
  __syncthreads();
  // P11: softmax bwd: T3 = A*(dA - rowsum(dA*A)) -> T3row(s3), T3T(s6)
  {
    int row = tid >> 2, q = tid & 3;
    float da[16], a[16], rs = 0.f;
    #pragma unroll
    for (int cc = 0; cc < 16; cc++){
      int col = q*16 + cc;
      da[cc] = b2f(Xr[row*72 + col]);
      a[cc]  = b2f(s7[row*72 + col]);
      rs += da[cc]*a[cc];
    }
    rs += __shfl_xor(rs, 1);
    rs += __shfl_xor(rs, 2);
    #pragma unroll
    for (int cc = 0; cc < 16; cc++){
      int col = q*16 + cc;
      unsigned short hh = f2b(a[cc] * (da[cc] - rs));
      s3[row*72 + col] = hh;
      s6[col*72 + row] = hh;
    }
  }
  __syncthreads();
  // P12: dv = A^T @ dHd -> dvT(Xr)
  mm64<false>(s9, s4, acc, M);
  storeT64(Xr, acc, M, 1.f);
  __syncthreads();
  // P13: dWv1 = X^T @ dv -> global
  mm64<false>(XT, Xr, acc, M);
  storeG64(g + ((size_t)(2*NCHUNK + chunk))*4096, acc, M, negLr);
  __syncthreads();
  // P14: dq = T3 @ K / 8 -> dqT(Xr)
  mm64<false>(s3, s10, acc, M);
  storeT64(Xr, acc, M, 0.125f);
  __syncthreads();
  // P15: dWq = X^T @ dq -> global
  mm64<false>(XT, Xr, acc, M);
  storeG64(g + ((size_t)(0*NCHUNK + chunk))*4096, acc, M, negLr);
  __syncthreads();
  // P16: dk = T3^T @ Q / 8 -> dkT(Xr)
  mm64<false>(s6, s8, acc, M);
  storeT64(Xr, acc, M, 0.125f);
  __syncthreads();
  // P17: dWk = X^T @ dk -> global
  mm64<false>(XT, Xr, acc, M);
  storeG64(g + ((size_t)(1*NCHUNK + chunk))*4096, acc, M, negLr);
}

// =====================================================================
// K5: double associative scan over chunks; in-place g -> per-chunk weights
// =====================================================================
__global__ __launch_bounds__(256) void k_scan(
    float* __restrict__ g, const float* __restrict__ mg, const float* __restrict__ dec,
    const float* __restrict__ wq, const float* __restrict__ wk,
    const float* __restrict__ wv1, const float* __restrict__ wv2)
{
  int idx = blockIdx.x * 256 + threadIdx.x;
  int e = idx & 4095;
  int bh = (idx >> 12) & 15;
  int name = idx >> 16;
  const float* past = (name == 0) ? wq : (name == 1) ? wk : (name == 2) ? wv1 : wv2;
  float base = past[e];
  float m = 0.f, u = 0.f;
  for (int t = 0; t < NC; t++){
    size_t off = ((size_t)(name*NCHUNK + bh*NC + t)) * 4096 + e;
    float su = g[off];
    float gm = mg[bh*NC + t];
    float dc = dec[bh*NC + t];
    m = gm * m + su;
    u = (1.f - dc) * u + m;
    g[off] = base + u;
  }
}

// =====================================================================
// K6: retrieval attention with per-chunk weights (MFMA bf16)
// grid = 1024 chunks, 256 threads, ~72KB LDS (2 blocks/CU)
// =====================================================================
__global__ __launch_bounds__(256, 2) void k_retrieve(
    const float* __restrict__ qb, const float* __restrict__ Wg, float* __restrict__ vals)
{
  __shared__ __align__(16) unsigned short sm[6*TS];
  __shared__ __align__(16) float SC[64*66];
  unsigned short *Xr = sm, *Wt = sm + TS, *Qr = sm + 2*TS,
                 *Kr = sm + 3*TS, *Vt = sm + 4*TS, *Hr = sm + 5*TS;
  unsigned short *Ar = (unsigned short*)SC;   // reuse score scratch for A
  int chunk = blockIdx.x;
  int bh = chunk >> 6, t = chunk & 63;
  int b = bh >> 3, h = bh & 7;
  int tid = threadIdx.x;
  MM M = mmctx();
  const float* xb = qb + ((size_t)(b*SEQ + t*CH)) * DI + h*DH;
  f32x4 acc[2][2];

  loadTile<true,false>(Xr, nullptr, xb, DI, tid);
  loadTile<false,true>(nullptr, Wt, Wg + ((size_t)(0*NCHUNK + chunk))*4096, 64, tid);
  __syncthreads();
  mm64<false>(Xr, Wt, acc, M); storeN64(Qr, acc, M, 1.f);
  __syncthreads();
  loadTile<false,true>(nullptr, Wt, Wg + ((size_t)(1*NCHUNK + chunk))*4096, 64, tid);
  __syncthreads();
  mm64<false>(Xr, Wt, acc, M); storeN64(Kr, acc, M, 1.f);
  __syncthreads();
  loadTile<false,true>(nullptr, Wt, Wg + ((size_t)(2*NCHUNK + chunk))*4096, 64, tid);
  __syncthreads();
  mm64<false>(Xr, Wt, acc, M); storeT64(Vt, acc, M, 1.f);
  __syncthreads();
  // S = Q K^T / 8 ; also prefetch Wv2^T
  mm64<false>(Qr, Kr, acc, M); storeSC(SC, acc, M, 0.125f);
  loadTile<false,true>(nullptr, Wt, Wg + ((size_t)(3*NCHUNK + chunk))*4096, 64, tid);
  __syncthreads();
  // causal softmax -> Ar (overlays SC after all reads)
  {
    int row = tid >> 2, q = tid & 3;
    float p[16];
    float mx = -1e30f;
    #pragma unroll
    for (int cc = 0; cc < 16; cc++){
      int col = q*16 + cc;
      float x = SC[row*66 + col];
      p[cc] = (col <= row) ? x : -1e9f;
      mx = fmaxf(mx, p[cc]);
    }
    mx = fmaxf(mx, __shfl_xor(mx, 1));
    mx = fmaxf(mx, __shfl_xor(mx, 2));
    float sum = 0.f;
    #pragma unroll
    for (int cc = 0; cc < 16; cc++){ p[cc] = __expf(p[cc] - mx); sum += p[cc]; }
    sum += __shfl_xor(sum, 1);
    sum += __shfl_xor(sum, 2);
    float inv = 1.f / sum;
    __syncthreads();   // all SC reads complete before overwrite
    #pragma unroll
    for (int cc = 0; cc < 16; cc++){
      int col = q*16 + cc;
      Ar[row*72 + col] = f2b(p[cc] * inv);
    }
  }
  __syncthreads();
  mm64<false>(Ar, Vt, acc, M); storeN64(Hr, acc, M, 1.f);
  __syncthreads();
  // out = silu(H) @ Wv2 -> vals f32
  mm64<true>(Hr, Wt, acc, M);
  #pragma unroll
  for (int rt = 0; rt < 2; rt++)
    #pragma unroll
    for (int ct = 0; ct < 2; ct++){
      int c  = M.colbase + ct*16 + M.lr;
      int mb = M.rowbase + rt*16 + M.lg*4;
      #pragma unroll
      for (int r = 0; r < 4; r++)
        vals[((size_t)(b*SEQ + t*CH + mb + r))*DI + h*DH + c] = acc[rt][ct][r];
    }
}

// =====================================================================
// K8: final rmsnorm + shift
// =====================================================================
__global__ __launch_bounds__(256) void k_outnorm(
    const float* __restrict__ tmp, const float* __restrict__ wpn, float* __restrict__ out)
{
  __shared__ float red[4];
  int row = blockIdx.x;
  int b = row / (SEQ - CH), r = row % (SEQ - CH);
  const float* src = tmp + ((size_t)b*SEQ + r) * DIM;
  float* dst = out + ((size_t)b*SEQ + r + CH) * DIM;
  int tid = threadIdx.x;
  float x0 = src[tid], x1 = src[tid + 256];
  float ss = block_sum256(x0*x0 + x1*x1, red, tid);
  float rinv = rsqrtf(ss / (float)DIM + 1e-6f);
  dst[tid]       = x0 * rinv * wpn[tid];
  dst[tid + 256] = x1 * rinv * wpn[tid + 256];
}

// =====================================================================
extern "C" void kernel_launch(void* const* d_in, const int* in_sizes, int n_in,
                              void* d_out, int out_size, void* d_ws, size_t ws_size,
                              hipStream_t stream)
{
  (void)in_sizes; (void)n_in; (void)ws_size;
  const float* seq   = (const float*)d_in[0];
  const float* wsn   = (const float*)d_in[1];
  const float* wrn   = (const float*)d_in[2];
  const float* wpn   = (const float*)d_in[3];
  const float* w_q   = (const float*)d_in[4];
  const float* w_kv  = (const float*)d_in[5];
  const float* wstep = (const float*)d_in[6];
  const float* wmom  = (const float*)d_in[7];
  const float* wdec  = (const float*)d_in[8];
  const float* wcomb = (const float*)d_in[9];
  const float* wq    = (const float*)d_in[10];
  const float* wk    = (const float*)d_in[11];
  const float* wv1   = (const float*)d_in[12];
  const float* wv2   = (const float*)d_in[13];
  float* out = (float*)d_out;

  float* ws  = (float*)d_ws;
  float* s    = ws;                      // 8192*512           (also vals)
  float* rsh  = s + (size_t)ROWS*DIM;    // 8192*512           (also tmp)
  float* kv   = rsh + (size_t)ROWS*DIM;  // 8192*1024
  float* qb   = kv + (size_t)ROWS*2*DI;  // 8192*512
  float* g    = qb + (size_t)ROWS*DI;    // 4*1024*4096
  float* lrp  = g + (size_t)4*NCHUNK*4096; // 8192*8
  float* mg   = lrp + (size_t)ROWS*HEADS;  // 1024
  float* dec  = mg + BH*NC;
  float* lrc  = dec + BH*NC;
  float* vals = s;
  float* tmp  = rsh;

  hipMemsetAsync(d_out, 0, (size_t)out_size * sizeof(float), stream);
  for (int b = 0; b < BATCH; b++)
    hipMemsetAsync(rsh + ((size_t)b*SEQ + (SEQ - CH))*DIM, 0,
                   (size_t)CH*DIM*sizeof(float), stream);

  k_store_norm<<<ROWS, 256, 0, stream>>>(seq, wsn, wrn, wstep, s, rsh, lrp);
  sgemm_kernel<<<dim3((2*DI)/64, ROWS/64), 256, 0, stream>>>(s, w_kv, kv, ROWS, 2*DI, DIM);
  k_stats<<<BATCH*NC, 256, 0, stream>>>(s, lrp, wmom, wdec, mg, dec, lrc);
  sgemm_kernel<<<dim3(DI/64, ROWS/64), 256, 0, stream>>>(rsh, w_q, qb, ROWS, DI, DIM);
  k_grads<<<NCHUNK, 256, 0, stream>>>(kv, wq, wk, wv1, wv2, lrc, g);
  k_scan<<<(4*BH*4096)/256, 256, 0, stream>>>(g, mg, dec, wq, wk, wv1, wv2);
  k_retrieve<<<NCHUNK, 256, 0, stream>>>(qb, g, vals);
  sgemm_kernel<<<dim3(DIM/64, ROWS/64), 256, 0, stream>>>(vals, wcomb, tmp, ROWS, DIM, DIM);
  k_outnorm<<<BATCH*(SEQ - CH), 256, 0, stream>>>(tmp, wpn, out);
}

// Round 4
// 345.894 us; speedup vs baseline: 2.1333x; 1.2963x over previous
//
#include <hip/hip_runtime.h>
#include <math.h>

#define LS 65  // f32 LDS row stride for 64x64 tiles

constexpr int BATCH = 2, SEQ = 4096, DIM = 512, HEADS = 8, DH = 64, CH = 64;
constexpr int NC = SEQ / CH;        // 64 chunks per (b,h)
constexpr int BH = BATCH * HEADS;   // 16
constexpr int NCHUNK = BH * NC;     // 1024
constexpr int ROWS = BATCH * SEQ;   // 8192
constexpr int DI = HEADS * DH;      // 512
constexpr int TS = 64 * 72;         // bf16 tile: 64 rows, stride 72 elems

typedef __attribute__((ext_vector_type(8))) short short8;
typedef __attribute__((ext_vector_type(4))) short short4v;
typedef __attribute__((ext_vector_type(4))) float f32x4;

__device__ inline float sigmoidf_(float x){ return 1.f/(1.f+__expf(-x)); }
__device__ inline float dsilu_f(float x){ float s = sigmoidf_(x); return s*(1.f + x*(1.f-s)); }

__device__ inline unsigned short f2b(float f){
  union { float f; unsigned int u; } c; c.f = f;
  unsigned int u = c.u;
  unsigned int r = (u + 0x7FFFu + ((u >> 16) & 1u)) >> 16;
  return (unsigned short)r;
}
__device__ inline float b2f(unsigned short h){
  union { unsigned int u; float f; } c; c.u = ((unsigned int)h) << 16;
  return c.f;
}

// ---- block-wide sum over 256 threads ----
__device__ inline float block_sum256(float v, float* red, int tid){
  #pragma unroll
  for (int m = 1; m < 64; m <<= 1) v += __shfl_xor(v, m);
  if ((tid & 63) == 0) red[tid >> 6] = v;
  __syncthreads();
  return red[0] + red[1] + red[2] + red[3];
}

// =====================================================================
// MFMA 64x64 building blocks (4 waves, each owns a 32x32 quadrant)
// =====================================================================
struct MM { int lr, lg, rowbase, colbase; };
__device__ inline MM mmctx(){
  int tid = threadIdx.x;
  int wid = tid >> 6, lane = tid & 63;
  MM m; m.lr = lane & 15; m.lg = lane >> 4;
  m.rowbase = (wid >> 1) * 32; m.colbase = (wid & 1) * 32;
  return m;
}

template<bool SILUA>
__device__ inline void mm64(const unsigned short* A, const unsigned short* B,
                            f32x4 (&acc)[2][2], const MM& m)
{
  #pragma unroll
  for (int rt = 0; rt < 2; rt++)
    #pragma unroll
    for (int ct = 0; ct < 2; ct++) acc[rt][ct] = (f32x4){0.f, 0.f, 0.f, 0.f};
  #pragma unroll
  for (int ks = 0; ks < 2; ks++){
    short8 a[2], b[2];
    #pragma unroll
    for (int rt = 0; rt < 2; rt++){
      a[rt] = *(const short8*)&A[(m.rowbase + rt*16 + m.lr)*72 + ks*32 + m.lg*8];
      if constexpr (SILUA){
        #pragma unroll
        for (int j = 0; j < 8; j++){
          float v = b2f((unsigned short)a[rt][j]);
          v = v * sigmoidf_(v);
          a[rt][j] = (short)f2b(v);
        }
      }
    }
    #pragma unroll
    for (int ct = 0; ct < 2; ct++)
      b[ct] = *(const short8*)&B[(m.colbase + ct*16 + m.lr)*72 + ks*32 + m.lg*8];
    #pragma unroll
    for (int rt = 0; rt < 2; rt++)
      #pragma unroll
      for (int ct = 0; ct < 2; ct++)
        acc[rt][ct] = __builtin_amdgcn_mfma_f32_16x16x32_bf16(a[rt], b[ct], acc[rt][ct], 0, 0, 0);
  }
}

__device__ inline void storeN64(unsigned short* R, const f32x4 (&acc)[2][2], const MM& m, float scale){
  #pragma unroll
  for (int rt = 0; rt < 2; rt++)
    #pragma unroll
    for (int ct = 0; ct < 2; ct++){
      int c  = m.colbase + ct*16 + m.lr;
      int mb = m.rowbase + rt*16 + m.lg*4;
      #pragma unroll
      for (int r = 0; r < 4; r++) R[(mb+r)*72 + c] = f2b(acc[rt][ct][r] * scale);
    }
}
__device__ inline void storeT64(unsigned short* T, const f32x4 (&acc)[2][2], const MM& m, float scale){
  #pragma unroll
  for (int rt = 0; rt < 2; rt++)
    #pragma unroll
    for (int ct = 0; ct < 2; ct++){
      int c  = m.colbase + ct*16 + m.lr;
      int mb = m.rowbase + rt*16 + m.lg*4;
      short4v p;
      #pragma unroll
      for (int r = 0; r < 4; r++) p[r] = (short)f2b(acc[rt][ct][r] * scale);
      *(short4v*)&T[c*72 + mb] = p;
    }
}
__device__ inline void storeSC(float* S, const f32x4 (&acc)[2][2], const MM& m, float scale){
  #pragma unroll
  for (int rt = 0; rt < 2; rt++)
    #pragma unroll
    for (int ct = 0; ct < 2; ct++){
      int c  = m.colbase + ct*16 + m.lr;
      int mb = m.rowbase + rt*16 + m.lg*4;
      #pragma unroll
      for (int r = 0; r < 4; r++) S[(mb+r)*66 + c] = acc[rt][ct][r] * scale;
    }
}
__device__ inline void storeG64(float* __restrict__ G, const f32x4 (&acc)[2][2], const MM& m, float scale){
  #pragma unroll
  for (int rt = 0; rt < 2; rt++)
    #pragma unroll
    for (int ct = 0; ct < 2; ct++){
      int c  = m.colbase + ct*16 + m.lr;
      int mb = m.rowbase + rt*16 + m.lg*4;
      #pragma unroll
      for (int r = 0; r < 4; r++) G[(mb+r)*64 + c] = acc[rt][ct][r] * scale;
    }
}

// load a 64x64 f32 global tile into bf16 LDS, row-major and/or transposed
template<bool DOR, bool DOT>
__device__ inline void loadTile(unsigned short* R, unsigned short* T,
                                const float* __restrict__ src, int stride, int tid){
  #pragma unroll
  for (int it = 0; it < 16; it++){
    int idx = it*256 + tid;
    int i = idx >> 6, j = idx & 63;
    unsigned short h = f2b(src[(size_t)i*stride + j]);
    if constexpr (DOR) R[i*72 + j] = h;
    if constexpr (DOT) T[j*72 + i] = h;
  }
}

// =====================================================================
// K0: weight transpose (f32): dst[C][R] <- src[R][C]
// grid = dim3(C/64, R/64)
// =====================================================================
__global__ __launch_bounds__(256) void k_wT(
    const float* __restrict__ src, float* __restrict__ dst, int R, int C)
{
  __shared__ float t[64][65];
  int c0 = blockIdx.x * 64, r0 = blockIdx.y * 64;
  int tid = threadIdx.x;
  #pragma unroll
  for (int it = 0; it < 16; it++){
    int idx = it*256 + tid;
    int i = idx >> 6, j = idx & 63;
    t[i][j] = src[(size_t)(r0+i)*C + c0 + j];
  }
  __syncthreads();
  #pragma unroll
  for (int it = 0; it < 16; it++){
    int idx = it*256 + tid;
    int i = idx >> 6, j = idx & 63;
    dst[(size_t)(c0+i)*R + r0 + j] = t[j][i];
  }
}

// =====================================================================
// K-GEMM (split-bf16, ~f32 accuracy): C[MxN] = A[MxK] @ B
// A f32 row-major; B pre-transposed f32 [N][K].
// Split in staging: hi=bf16(v), lo=bf16(v-hi); acc = Ah*Bh + Ah*Bl + Al*Bh
// 128x128 tile, BK=64, 4 waves, 72KB LDS -> 2 blocks/CU
// =====================================================================
__global__ __launch_bounds__(256, 2) void k_gemm_split(
    const float* __restrict__ A, const float* __restrict__ BT,
    float* __restrict__ C, int M, int N, int K)
{
  __shared__ __align__(16) unsigned short Ah[128*72];
  __shared__ __align__(16) unsigned short Al[128*72];
  __shared__ __align__(16) unsigned short Bh[128*72];
  __shared__ __align__(16) unsigned short Bl[128*72];
  int tid = threadIdx.x;
  int m0 = blockIdx.y * 128, n0 = blockIdx.x * 128;
  int wid = tid >> 6, lane = tid & 63;
  int lr = lane & 15, lg = lane >> 4;
  int wr = (wid >> 1) * 64, wc = (wid & 1) * 64;
  f32x4 acc[4][4];
  #pragma unroll
  for (int r = 0; r < 4; r++)
    #pragma unroll
    for (int c = 0; c < 4; c++) acc[r][c] = (f32x4){0.f,0.f,0.f,0.f};

  for (int k0 = 0; k0 < K; k0 += 64){
    #pragma unroll
    for (int it = 0; it < 8; it++){
      int c = it*256 + tid;               // 0..2047
      int row = c >> 4, col4 = (c & 15)*4;
      float4 va = *(const float4*)&A[(size_t)(m0+row)*K + k0 + col4];
      float4 vb = *(const float4*)&BT[(size_t)(n0+row)*K + k0 + col4];
      short4v ah, al, bh, bl;
      float av[4] = {va.x, va.y, va.z, va.w};
      float bv[4] = {vb.x, vb.y, vb.z, vb.w};
      #pragma unroll
      for (int j = 0; j < 4; j++){
        unsigned short h = f2b(av[j]);
        ah[j] = (short)h; al[j] = (short)f2b(av[j] - b2f(h));
        unsigned short g = f2b(bv[j]);
        bh[j] = (short)g; bl[j] = (short)f2b(bv[j] - b2f(g));
      }
      *(short4v*)&Ah[row*72 + col4] = ah;
      *(short4v*)&Al[row*72 + col4] = al;
      *(short4v*)&Bh[row*72 + col4] = bh;
      *(short4v*)&Bl[row*72 + col4] = bl;
    }
    __syncthreads();
    #pragma unroll
    for (int ks = 0; ks < 2; ks++){
      short8 ah[4], al[4], bh[4], bl[4];
      #pragma unroll
      for (int i = 0; i < 4; i++){
        int ao = (wr + i*16 + lr)*72 + ks*32 + lg*8;
        int bo = (wc + i*16 + lr)*72 + ks*32 + lg*8;
        ah[i] = *(const short8*)&Ah[ao];
        al[i] = *(const short8*)&Al[ao];
        bh[i] = *(const short8*)&Bh[bo];
        bl[i] = *(const short8*)&Bl[bo];
      }
      #pragma unroll
      for (int r = 0; r < 4; r++)
        #pragma unroll
        for (int c = 0; c < 4; c++){
          acc[r][c] = __builtin_amdgcn_mfma_f32_16x16x32_bf16(ah[r], bh[c], acc[r][c], 0, 0, 0);
          acc[r][c] = __builtin_amdgcn_mfma_f32_16x16x32_bf16(ah[r], bl[c], acc[r][c], 0, 0, 0);
          acc[r][c] = __builtin_amdgcn_mfma_f32_16x16x32_bf16(al[r], bh[c], acc[r][c], 0, 0, 0);
        }
    }
    __syncthreads();
  }
  #pragma unroll
  for (int rt = 0; rt < 4; rt++)
    #pragma unroll
    for (int ct = 0; ct < 4; ct++){
      int col = n0 + wc + ct*16 + lr;
      int rowb = m0 + wr + rt*16 + lg*4;
      #pragma unroll
      for (int r = 0; r < 4; r++)
        C[(size_t)(rowb+r)*N + col] = acc[rt][ct][r];
    }
}

// =====================================================================
// K1: store-rmsnorm + retrieve-rmsnorm(shifted) + per-position lr (f32 out)
// =====================================================================
__global__ __launch_bounds__(256) void k_store_norm(
    const float* __restrict__ seq, const float* __restrict__ wsn,
    const float* __restrict__ wrn, const float* __restrict__ wstep,
    float* __restrict__ s, float* __restrict__ rsh, float* __restrict__ lrp)
{
  __shared__ float srow[DIM];
  __shared__ float red[4];
  int row = blockIdx.x;
  int b = row >> 12, t = row & 4095;
  const float* x = seq + (size_t)row * DIM;
  int tid = threadIdx.x;
  float x0 = x[tid], x1 = x[tid + 256];
  float ss = block_sum256(x0*x0 + x1*x1, red, tid);
  float rinv = rsqrtf(ss / (float)DIM + 1e-6f);
  float s0 = x0 * rinv * wsn[tid], s1 = x1 * rinv * wsn[tid + 256];
  s[(size_t)row*DIM + tid] = s0;
  s[(size_t)row*DIM + tid + 256] = s1;
  srow[tid] = s0; srow[tid + 256] = s1;
  if (t >= CH){
    float* rr = rsh + ((size_t)b*SEQ + (t - CH)) * DIM;
    rr[tid]       = x0 * rinv * wrn[tid];
    rr[tid + 256] = x1 * rinv * wrn[tid + 256];
  }
  __syncthreads();
  int gh = tid >> 5, l = tid & 31;
  float acc = 0.f;
  for (int e = l; e < DIM; e += 32) acc += srow[e] * wstep[e*HEADS + gh];
  #pragma unroll
  for (int m = 1; m < 32; m <<= 1) acc += __shfl_xor(acc, m);
  if (l == 0){
    float sg = sigmoidf_(acc);
    lrp[(size_t)row*HEADS + gh] = __expf(-15.f * sg);
  }
}

// =====================================================================
// K3: chunk stats -> mom_gate, decay, lr (chunk mean)
// =====================================================================
__global__ __launch_bounds__(256) void k_stats(
    const float* __restrict__ s, const float* __restrict__ lrp,
    const float* __restrict__ wmom, const float* __restrict__ wdec,
    float* __restrict__ mg, float* __restrict__ dec, float* __restrict__ lrc)
{
  __shared__ float smean[DIM];
  int blk = blockIdx.x;
  int b = blk >> 6, ch = blk & 63;
  int tid = threadIdx.x;
  const float* base = s + ((size_t)(b*SEQ + ch*CH)) * DIM;
  for (int e = tid; e < DIM; e += 256){
    float acc = 0.f;
    for (int i = 0; i < CH; i++) acc += base[(size_t)i*DIM + e];
    smean[e] = acc * (1.f/CH);
  }
  __syncthreads();
  int gh = tid >> 5, l = tid & 31;
  float am = 0.f, ad = 0.f;
  for (int e = l; e < DIM; e += 32){
    float v = smean[e];
    am += v * wmom[e*HEADS + gh];
    ad += v * wdec[e*HEADS + gh];
  }
  const float* lrbase = lrp + ((size_t)(b*SEQ + ch*CH)) * HEADS + gh;
  float al = lrbase[(size_t)l*HEADS] + lrbase[(size_t)(l+32)*HEADS];
  #pragma unroll
  for (int m = 1; m < 32; m <<= 1){
    am += __shfl_xor(am, m);
    ad += __shfl_xor(ad, m);
    al += __shfl_xor(al, m);
  }
  if (l == 0){
    int o = (b*HEADS + gh)*NC + ch;
    mg[o]  = sigmoidf_(am);
    dec[o] = sigmoidf_(ad);
    lrc[o] = al * (1.f/CH);
  }
}

// =====================================================================
// K4: per-chunk attention fwd+bwd -> surprise = -lr * grad  (MFMA bf16)
// f32 kv input (f32 regression target)
// =====================================================================
__global__ __launch_bounds__(256, 1) void k_grads(
    const float* __restrict__ kv,
    const float* __restrict__ wq, const float* __restrict__ wk,
    const float* __restrict__ wv1, const float* __restrict__ wv2,
    const float* __restrict__ lrc, float* __restrict__ g)
{
  __shared__ __align__(16) unsigned short sm[12*TS];
  __shared__ __align__(16) float SC[64*66];
  unsigned short *Xr = sm,        *XT = sm + TS,
                 *s2 = sm + 2*TS, *s3 = sm + 3*TS, *s4 = sm + 4*TS,
                 *s5 = sm + 5*TS, *s6 = sm + 6*TS, *s7 = sm + 7*TS,
                 *s8 = sm + 8*TS, *s9 = sm + 9*TS, *s10 = sm + 10*TS,
                 *s11 = sm + 11*TS;
  int chunk = blockIdx.x;
  int bh = chunk >> 6, t = chunk & 63;
  int b = bh >> 3, h = bh & 7;
  int tid = threadIdx.x;
  MM M = mmctx();
  const float* xbase = kv + ((size_t)(b*SEQ + t*CH)) * (2*DI) + h*DH;
  const float* tbase = xbase + DI;   // values half (f32 target)
  float negLr = -lrc[bh*NC + t];
  f32x4 acc[2][2];

  loadTile<true,true>(Xr, XT, xbase, 2*DI, tid);
  loadTile<false,true>(nullptr, s2, wq, 64, tid);
  loadTile<false,true>(nullptr, s3, wk, 64, tid);
  loadTile<false,true>(nullptr, s4, wv1, 64, tid);
  loadTile<true,true>(s6, s5, wv2, 64, tid);
  __syncthreads();
  mm64<false>(Xr, s2, acc, M);
  storeN64(s7, acc, M, 1.f); storeT64(s8, acc, M, 1.f);
  __syncthreads();
  mm64<false>(Xr, s3, acc, M);
  storeN64(s9, acc, M, 1.f); storeT64(s10, acc, M, 1.f);
  __syncthreads();
  mm64<false>(Xr, s4, acc, M);
  storeN64(s11, acc, M, 1.f); storeT64(s2, acc, M, 1.f);
  __syncthreads();
  mm64<false>(s7, s9, acc, M);
  storeSC(SC, acc, M, 0.125f);
  __syncthreads();
  {
    int row = tid >> 2, q = tid & 3;
    float p[16];
    float mx = -1e30f;
    #pragma unroll
    for (int cc = 0; cc < 16; cc++){
      int col = q*16 + cc;
      float x = SC[row*66 + col];
      p[cc] = (col <= row) ? x : -1e9f;
      mx = fmaxf(mx, p[cc]);
    }
    mx = fmaxf(mx, __shfl_xor(mx, 1));
    mx = fmaxf(mx, __shfl_xor(mx, 2));
    float sum = 0.f;
    #pragma unroll
    for (int cc = 0; cc < 16; cc++){ p[cc] = __expf(p[cc] - mx); sum += p[cc]; }
    sum += __shfl_xor(sum, 1);
    sum += __shfl_xor(sum, 2);
    float inv = 1.f / sum;
    #pragma unroll
    for (int cc = 0; cc < 16; cc++){
      int col = q*16 + cc;
      unsigned short hh = f2b(p[cc] * inv);
      s7[row*72 + col] = hh;
      s9[col*72 + row] = hh;
    }
  }
  __syncthreads();
  mm64<false>(s7, s2, acc, M);
  storeN64(s3, acc, M, 1.f); storeT64(s4, acc, M, 1.f);
  __syncthreads();
  mm64<true>(s3, s5, acc, M);
  #pragma unroll
  for (int rt = 0; rt < 2; rt++)
    #pragma unroll
    for (int ct = 0; ct < 2; ct++){
      int c  = M.colbase + ct*16 + M.lr;
      int mb = M.rowbase + rt*16 + M.lg*4;
      #pragma unroll
      for (int r = 0; r < 4; r++){
        float t2 = (acc[rt][ct][r] - tbase[(size_t)(mb+r)*(2*DI) + c]) * (2.f/64.f);
        unsigned short hh = f2b(t2);
        Xr[(mb+r)*72 + c] = hh;
        s2[c*72 + (mb+r)] = hh;
      }
    }
  __syncthreads();
  mm64<true>(s4, s2, acc, M);
  storeG64(g + ((size_t)(3*NCHUNK + chunk))*4096, acc, M, negLr);
  __syncthreads();
  mm64<false>(Xr, s6, acc, M);
  #pragma unroll
  for (int rt = 0; rt < 2; rt++)
    #pragma unroll
    for (int ct = 0; ct < 2; ct++){
      int c  = M.colbase + ct*16 + M.lr;
      int mb = M.rowbase + rt*16 + M.lg*4;
      #pragma unroll
      for (int r = 0; r < 4; r++){
        float x = b2f(s3[(mb+r)*72 + c]);
        float d = acc[rt][ct][r] * dsilu_f(x);
        unsigned short hh = f2b(d);
        s2[(mb+r)*72 + c] = hh;
        s4[c*72 + (mb+r)] = hh;
      }
    }
  __syncthreads();
  mm64<false>(s2, s11, acc, M);
  storeN64(Xr, acc, M, 1.f);
  __syncthreads();
  {
    int row = tid >> 2, q = tid & 3;
    float da[16], a[16], rs = 0.f;
    #pragma unroll
    for (int cc = 0; cc < 16; cc++){
      int col = q*16 + cc;
      da[cc] = b2f(Xr[row*72 + col]);
      a[cc]  = b2f(s7[row*72 + col]);
      rs += da[cc]*a[cc];
    }
    rs += __shfl_xor(rs, 1);
    rs += __shfl_xor(rs, 2);
    #pragma unroll
    for (int cc = 0; cc < 16; cc++){
      int col = q*16 + cc;
      unsigned short hh = f2b(a[cc] * (da[cc] - rs));
      s3[row*72 + col] = hh;
      s6[col*72 + row] = hh;
    }
  }
  __syncthreads();
  mm64<false>(s9, s4, acc, M);
  storeT64(Xr, acc, M, 1.f);
  __syncthreads();
  mm64<false>(XT, Xr, acc, M);
  storeG64(g + ((size_t)(2*NCHUNK + chunk))*4096, acc, M, negLr);
  __syncthreads();
  mm64<false>(s3, s10, acc, M);
  storeT64(Xr, acc, M, 0.125f);
  __syncthreads();
  mm64<false>(XT, Xr, acc, M);
  storeG64(g + ((size_t)(0*NCHUNK + chunk))*4096, acc, M, negLr);
  __syncthreads();
  mm64<false>(s6, s8, acc, M);
  storeT64(Xr, acc, M, 0.125f);
  __syncthreads();
  mm64<false>(XT, Xr, acc, M);
  storeG64(g + ((size_t)(1*NCHUNK + chunk))*4096, acc, M, negLr);
}

// =====================================================================
// K5: double associative scan over chunks; in-place g -> per-chunk weights
// =====================================================================
__global__ __launch_bounds__(256) void k_scan(
    float* __restrict__ g, const float* __restrict__ mg, const float* __restrict__ dec,
    const float* __restrict__ wq, const float* __restrict__ wk,
    const float* __restrict__ wv1, const float* __restrict__ wv2)
{
  int idx = blockIdx.x * 256 + threadIdx.x;
  int e = idx & 4095;
  int bh = (idx >> 12) & 15;
  int name = idx >> 16;
  const float* past = (name == 0) ? wq : (name == 1) ? wk : (name == 2) ? wv1 : wv2;
  float base = past[e];
  float m = 0.f, u = 0.f;
  for (int t = 0; t < NC; t++){
    size_t off = ((size_t)(name*NCHUNK + bh*NC + t)) * 4096 + e;
    float su = g[off];
    float gm = mg[bh*NC + t];
    float dc = dec[bh*NC + t];
    m = gm * m + su;
    u = (1.f - dc) * u + m;
    g[off] = base + u;
  }
}

// =====================================================================
// K6: retrieval attention with per-chunk weights (MFMA bf16; f32 in/out)
// =====================================================================
__global__ __launch_bounds__(256, 2) void k_retrieve(
    const float* __restrict__ qb, const float* __restrict__ Wg, float* __restrict__ vals)
{
  __shared__ __align__(16) unsigned short sm[6*TS];
  __shared__ __align__(16) float SC[64*66];
  unsigned short *Xr = sm, *Wt = sm + TS, *Qr = sm + 2*TS,
                 *Kr = sm + 3*TS, *Vt = sm + 4*TS, *Hr = sm + 5*TS;
  unsigned short *Ar = (unsigned short*)SC;
  int chunk = blockIdx.x;
  int bh = chunk >> 6, t = chunk & 63;
  int b = bh >> 3, h = bh & 7;
  int tid = threadIdx.x;
  MM M = mmctx();
  const float* xb = qb + ((size_t)(b*SEQ + t*CH)) * DI + h*DH;
  f32x4 acc[2][2];

  loadTile<true,false>(Xr, nullptr, xb, DI, tid);
  loadTile<false,true>(nullptr, Wt, Wg + ((size_t)(0*NCHUNK + chunk))*4096, 64, tid);
  __syncthreads();
  mm64<false>(Xr, Wt, acc, M); storeN64(Qr, acc, M, 1.f);
  __syncthreads();
  loadTile<false,true>(nullptr, Wt, Wg + ((size_t)(1*NCHUNK + chunk))*4096, 64, tid);
  __syncthreads();
  mm64<false>(Xr, Wt, acc, M); storeN64(Kr, acc, M, 1.f);
  __syncthreads();
  loadTile<false,true>(nullptr, Wt, Wg + ((size_t)(2*NCHUNK + chunk))*4096, 64, tid);
  __syncthreads();
  mm64<false>(Xr, Wt, acc, M); storeT64(Vt, acc, M, 1.f);
  __syncthreads();
  mm64<false>(Qr, Kr, acc, M); storeSC(SC, acc, M, 0.125f);
  loadTile<false,true>(nullptr, Wt, Wg + ((size_t)(3*NCHUNK + chunk))*4096, 64, tid);
  __syncthreads();
  {
    int row = tid >> 2, q = tid & 3;
    float p[16];
    float mx = -1e30f;
    #pragma unroll
    for (int cc = 0; cc < 16; cc++){
      int col = q*16 + cc;
      float x = SC[row*66 + col];
      p[cc] = (col <= row) ? x : -1e9f;
      mx = fmaxf(mx, p[cc]);
    }
    mx = fmaxf(mx, __shfl_xor(mx, 1));
    mx = fmaxf(mx, __shfl_xor(mx, 2));
    float sum = 0.f;
    #pragma unroll
    for (int cc = 0; cc < 16; cc++){ p[cc] = __expf(p[cc] - mx); sum += p[cc]; }
    sum += __shfl_xor(sum, 1);
    sum += __shfl_xor(sum, 2);
    float inv = 1.f / sum;
    __syncthreads();
    #pragma unroll
    for (int cc = 0; cc < 16; cc++){
      int col = q*16 + cc;
      Ar[row*72 + col] = f2b(p[cc] * inv);
    }
  }
  __syncthreads();
  mm64<false>(Ar, Vt, acc, M); storeN64(Hr, acc, M, 1.f);
  __syncthreads();
  mm64<true>(Hr, Wt, acc, M);
  #pragma unroll
  for (int rt = 0; rt < 2; rt++)
    #pragma unroll
    for (int ct = 0; ct < 2; ct++){
      int c  = M.colbase + ct*16 + M.lr;
      int mb = M.rowbase + rt*16 + M.lg*4;
      #pragma unroll
      for (int r = 0; r < 4; r++)
        vals[((size_t)(b*SEQ + t*CH + mb + r))*DI + h*DH + c] = acc[rt][ct][r];
    }
}

// =====================================================================
// K8: final rmsnorm + shift
// =====================================================================
__global__ __launch_bounds__(256) void k_outnorm(
    const float* __restrict__ tmp, const float* __restrict__ wpn, float* __restrict__ out)
{
  __shared__ float red[4];
  int row = blockIdx.x;
  int b = row / (SEQ - CH), r = row % (SEQ - CH);
  const float* src = tmp + ((size_t)b*SEQ + r) * DIM;
  float* dst = out + ((size_t)b*SEQ + r + CH) * DIM;
  int tid = threadIdx.x;
  float x0 = src[tid], x1 = src[tid + 256];
  float ss = block_sum256(x0*x0 + x1*x1, red, tid);
  float rinv = rsqrtf(ss / (float)DIM + 1e-6f);
  dst[tid]       = x0 * rinv * wpn[tid];
  dst[tid + 256] = x1 * rinv * wpn[tid + 256];
}

// =====================================================================
extern "C" void kernel_launch(void* const* d_in, const int* in_sizes, int n_in,
                              void* d_out, int out_size, void* d_ws, size_t ws_size,
                              hipStream_t stream)
{
  (void)in_sizes; (void)n_in; (void)ws_size;
  const float* seq   = (const float*)d_in[0];
  const float* wsn   = (const float*)d_in[1];
  const float* wrn   = (const float*)d_in[2];
  const float* wpn   = (const float*)d_in[3];
  const float* w_q   = (const float*)d_in[4];
  const float* w_kv  = (const float*)d_in[5];
  const float* wstep = (const float*)d_in[6];
  const float* wmom  = (const float*)d_in[7];
  const float* wdec  = (const float*)d_in[8];
  const float* wcomb = (const float*)d_in[9];
  const float* wq    = (const float*)d_in[10];
  const float* wk    = (const float*)d_in[11];
  const float* wv1   = (const float*)d_in[12];
  const float* wv2   = (const float*)d_in[13];
  float* out = (float*)d_out;

  float* ws  = (float*)d_ws;
  float* s    = ws;                        // 8192*512  (also vals)
  float* rsh  = s + (size_t)ROWS*DIM;      // 8192*512  (also tmp)
  float* kv   = rsh + (size_t)ROWS*DIM;    // 8192*1024
  float* qb   = kv + (size_t)ROWS*2*DI;    // 8192*512
  float* g    = qb + (size_t)ROWS*DI;      // 4*1024*4096
  float* lrp  = g + (size_t)4*NCHUNK*4096; // 8192*8
  float* mg   = lrp + (size_t)ROWS*HEADS;  // 1024
  float* dec  = mg + BH*NC;
  float* lrc  = dec + BH*NC;
  float* wkvT   = lrc + BH*NC;             // 1024*512
  float* wqT    = wkvT + (size_t)(2*DI)*DIM;   // 512*512
  float* wcombT = wqT + (size_t)DI*DIM;        // 512*512
  float* vals = s;
  float* tmp  = rsh;

  hipMemsetAsync(d_out, 0, (size_t)out_size * sizeof(float), stream);
  for (int b = 0; b < BATCH; b++)
    hipMemsetAsync(rsh + ((size_t)b*SEQ + (SEQ - CH))*DIM, 0,
                   (size_t)CH*DIM*sizeof(float), stream);

  // weight transposes (f32 [N][K])
  k_wT<<<dim3((2*DI)/64, DIM/64), 256, 0, stream>>>(w_kv, wkvT, DIM, 2*DI);
  k_wT<<<dim3(DI/64, DIM/64), 256, 0, stream>>>(w_q, wqT, DIM, DI);
  k_wT<<<dim3(DIM/64, DI/64), 256, 0, stream>>>(wcomb, wcombT, DI, DIM);

  k_store_norm<<<ROWS, 256, 0, stream>>>(seq, wsn, wrn, wstep, s, rsh, lrp);
  k_gemm_split<<<dim3((2*DI)/128, ROWS/128), 256, 0, stream>>>(s, wkvT, kv, ROWS, 2*DI, DIM);
  k_stats<<<BATCH*NC, 256, 0, stream>>>(s, lrp, wmom, wdec, mg, dec, lrc);
  k_gemm_split<<<dim3(DI/128, ROWS/128), 256, 0, stream>>>(rsh, wqT, qb, ROWS, DI, DIM);
  k_grads<<<NCHUNK, 256, 0, stream>>>(kv, wq, wk, wv1, wv2, lrc, g);
  k_scan<<<(4*BH*4096)/256, 256, 0, stream>>>(g, mg, dec, wq, wk, wv1, wv2);
  k_retrieve<<<NCHUNK, 256, 0, stream>>>(qb, g, vals);
  k_gemm_split<<<dim3(DIM/128, ROWS/128), 256, 0, stream>>>(vals, wcombT, tmp, ROWS, DIM, DIM);
  k_outnorm<<<BATCH*(SEQ - CH), 256, 0, stream>>>(tmp, wpn, out);
}

// Round 5
// 240.777 us; speedup vs baseline: 3.0647x; 1.4366x over previous
//
#include <hip/hip_runtime.h>
#include <math.h>

constexpr int BATCH = 2, SEQ = 4096, DIM = 512, HEADS = 8, DH = 64, CH = 64;
constexpr int NC = SEQ / CH;        // 64 chunks per (b,h)
constexpr int BH = BATCH * HEADS;   // 16
constexpr int NCHUNK = BH * NC;     // 1024
constexpr int ROWS = BATCH * SEQ;   // 8192
constexpr int DI = HEADS * DH;      // 512
constexpr int TS = 64 * 72;         // bf16 tile: 64 rows, stride 72 elems

typedef __attribute__((ext_vector_type(8))) short short8;
typedef __attribute__((ext_vector_type(4))) short short4v;
typedef __attribute__((ext_vector_type(4))) float f32x4;

__device__ inline float sigmoidf_(float x){ return 1.f/(1.f+__expf(-x)); }
__device__ inline float dsilu_f(float x){ float s = sigmoidf_(x); return s*(1.f + x*(1.f-s)); }

__device__ inline unsigned short f2b(float f){
  union { float f; unsigned int u; } c; c.f = f;
  unsigned int u = c.u;
  unsigned int r = (u + 0x7FFFu + ((u >> 16) & 1u)) >> 16;
  return (unsigned short)r;
}
__device__ inline float b2f(unsigned short h){
  union { unsigned int u; float f; } c; c.u = ((unsigned int)h) << 16;
  return c.f;
}

__device__ inline void cstore(float* p, float v){ *p = v; }
__device__ inline void cstore(unsigned short* p, float v){ *p = f2b(v); }

// =====================================================================
// 8-wave MFMA 64x64 building blocks (512 threads).
// Wave wid: rows [(wid>>1)*16, +16), cols [(wid&1)*32, +32) (2 16x16 tiles)
// A-tile: M x K row-major bf16 stride 72; B-tile: N x K row-major stride 72
// =====================================================================
struct MM { int lr, lg, rowbase, colbase; };
__device__ inline MM mmctx(){
  int tid = threadIdx.x;
  int wid = tid >> 6, lane = tid & 63;
  MM m; m.lr = lane & 15; m.lg = lane >> 4;
  m.rowbase = (wid >> 1) * 16; m.colbase = (wid & 1) * 32;
  return m;
}

template<bool SILUA>
__device__ inline void mm64(const unsigned short* A, const unsigned short* B,
                            f32x4 (&acc)[2], const MM& m)
{
  acc[0] = (f32x4){0.f,0.f,0.f,0.f};
  acc[1] = (f32x4){0.f,0.f,0.f,0.f};
  #pragma unroll
  for (int ks = 0; ks < 2; ks++){
    short8 a = *(const short8*)&A[(m.rowbase + m.lr)*72 + ks*32 + m.lg*8];
    if constexpr (SILUA){
      #pragma unroll
      for (int j = 0; j < 8; j++){
        float v = b2f((unsigned short)a[j]);
        v = v * sigmoidf_(v);
        a[j] = (short)f2b(v);
      }
    }
    #pragma unroll
    for (int ct = 0; ct < 2; ct++){
      short8 b = *(const short8*)&B[(m.colbase + ct*16 + m.lr)*72 + ks*32 + m.lg*8];
      acc[ct] = __builtin_amdgcn_mfma_f32_16x16x32_bf16(a, b, acc[ct], 0, 0, 0);
    }
  }
}

__device__ inline void storeN64(unsigned short* R, const f32x4 (&acc)[2], const MM& m, float scale){
  #pragma unroll
  for (int ct = 0; ct < 2; ct++){
    int c  = m.colbase + ct*16 + m.lr;
    int mb = m.rowbase + m.lg*4;
    #pragma unroll
    for (int r = 0; r < 4; r++) R[(mb+r)*72 + c] = f2b(acc[ct][r] * scale);
  }
}
__device__ inline void storeT64(unsigned short* T, const f32x4 (&acc)[2], const MM& m, float scale){
  #pragma unroll
  for (int ct = 0; ct < 2; ct++){
    int c  = m.colbase + ct*16 + m.lr;
    int mb = m.rowbase + m.lg*4;
    short4v p;
    #pragma unroll
    for (int r = 0; r < 4; r++) p[r] = (short)f2b(acc[ct][r] * scale);
    *(short4v*)&T[c*72 + mb] = p;
  }
}
__device__ inline void storeSC(float* S, const f32x4 (&acc)[2], const MM& m, float scale){
  #pragma unroll
  for (int ct = 0; ct < 2; ct++){
    int c  = m.colbase + ct*16 + m.lr;
    int mb = m.rowbase + m.lg*4;
    #pragma unroll
    for (int r = 0; r < 4; r++) S[(mb+r)*66 + c] = acc[ct][r] * scale;
  }
}
__device__ inline void storeG64(float* __restrict__ G, const f32x4 (&acc)[2], const MM& m, float scale){
  #pragma unroll
  for (int ct = 0; ct < 2; ct++){
    int c  = m.colbase + ct*16 + m.lr;
    int mb = m.rowbase + m.lg*4;
    #pragma unroll
    for (int r = 0; r < 4; r++) G[(mb+r)*64 + c] = acc[ct][r] * scale;
  }
}

// f32 global 64x64 -> bf16 LDS (row and/or transposed); 512 threads
template<bool DOR, bool DOT>
__device__ inline void loadTile(unsigned short* R, unsigned short* T,
                                const float* __restrict__ src, int stride, int tid){
  #pragma unroll
  for (int it = 0; it < 8; it++){
    int idx = it*512 + tid;
    int i = idx >> 6, j = idx & 63;
    unsigned short h = f2b(src[(size_t)i*stride + j]);
    if constexpr (DOR) R[i*72 + j] = h;
    if constexpr (DOT) T[j*72 + i] = h;
  }
}
// bf16 global 64x64 -> row LDS; 512 threads (one short8 each)
__device__ inline void loadTileBrow(unsigned short* R, const unsigned short* __restrict__ src,
                                    int stride, int tid){
  int i = tid >> 3, j8 = (tid & 7) * 8;
  *(short8*)&R[i*72 + j8] = *(const short8*)&src[(size_t)i*stride + j8];
}

// =====================================================================
// K0: weight transpose+split: dst_{hi,lo}[C][R] bf16 <- src[R][C] f32
// =====================================================================
__global__ __launch_bounds__(256) void k_wT(
    const float* __restrict__ src, unsigned short* __restrict__ dhi,
    unsigned short* __restrict__ dlo, int R, int C)
{
  __shared__ float t[64][65];
  int c0 = blockIdx.x * 64, r0 = blockIdx.y * 64;
  int tid = threadIdx.x;
  #pragma unroll
  for (int it = 0; it < 16; it++){
    int idx = it*256 + tid;
    int i = idx >> 6, j = idx & 63;
    t[i][j] = src[(size_t)(r0+i)*C + c0 + j];
  }
  __syncthreads();
  #pragma unroll
  for (int it = 0; it < 16; it++){
    int idx = it*256 + tid;
    int i = idx >> 6, j = idx & 63;
    float v = t[j][i];
    unsigned short hi = f2b(v);
    dhi[(size_t)(c0+i)*R + r0 + j] = hi;
    dlo[(size_t)(c0+i)*R + r0 + j] = f2b(v - b2f(hi));
  }
}

// =====================================================================
// K-GEMM 3-pass split: C = A @ B^T, A/B given as pre-split hi/lo bf16,
// A [M][K], B [N][K]. 128x128 tile, BK=64, 4 waves, ~74KB LDS -> 2 blk/CU
// =====================================================================
template<typename OutT>
__global__ __launch_bounds__(256) void k_gemm3(
    const unsigned short* __restrict__ Ahg, const unsigned short* __restrict__ Alg,
    const unsigned short* __restrict__ Bhg, const unsigned short* __restrict__ Blg,
    OutT* __restrict__ C, int M, int N, int K)
{
  __shared__ __align__(16) unsigned short AhS[128*72];
  __shared__ __align__(16) unsigned short AlS[128*72];
  __shared__ __align__(16) unsigned short BhS[128*72];
  __shared__ __align__(16) unsigned short BlS[128*72];
  int tid = threadIdx.x;
  int m0 = blockIdx.y * 128, n0 = blockIdx.x * 128;
  int wid = tid >> 6, lane = tid & 63;
  int lr = lane & 15, lg = lane >> 4;
  int wr = (wid >> 1) * 64, wc = (wid & 1) * 64;
  f32x4 acc[4][4];
  #pragma unroll
  for (int r = 0; r < 4; r++)
    #pragma unroll
    for (int c = 0; c < 4; c++) acc[r][c] = (f32x4){0.f,0.f,0.f,0.f};

  for (int k0 = 0; k0 < K; k0 += 64){
    #pragma unroll
    for (int it = 0; it < 4; it++){
      int idx = it*256 + tid;
      int row = idx >> 3, col8 = (idx & 7) * 8;
      size_t ga = (size_t)(m0+row)*K + k0 + col8;
      size_t gb = (size_t)(n0+row)*K + k0 + col8;
      *(short8*)&AhS[row*72 + col8] = *(const short8*)&Ahg[ga];
      *(short8*)&AlS[row*72 + col8] = *(const short8*)&Alg[ga];
      *(short8*)&BhS[row*72 + col8] = *(const short8*)&Bhg[gb];
      *(short8*)&BlS[row*72 + col8] = *(const short8*)&Blg[gb];
    }
    __syncthreads();
    #pragma unroll
    for (int ks = 0; ks < 2; ks++){
      short8 ah[4], al[4], bh[4], bl[4];
      #pragma unroll
      for (int i = 0; i < 4; i++){
        int ao = (wr + i*16 + lr)*72 + ks*32 + lg*8;
        int bo = (wc + i*16 + lr)*72 + ks*32 + lg*8;
        ah[i] = *(const short8*)&AhS[ao];
        al[i] = *(const short8*)&AlS[ao];
        bh[i] = *(const short8*)&BhS[bo];
        bl[i] = *(const short8*)&BlS[bo];
      }
      #pragma unroll
      for (int r = 0; r < 4; r++)
        #pragma unroll
        for (int c = 0; c < 4; c++){
          acc[r][c] = __builtin_amdgcn_mfma_f32_16x16x32_bf16(ah[r], bh[c], acc[r][c], 0, 0, 0);
          acc[r][c] = __builtin_amdgcn_mfma_f32_16x16x32_bf16(ah[r], bl[c], acc[r][c], 0, 0, 0);
          acc[r][c] = __builtin_amdgcn_mfma_f32_16x16x32_bf16(al[r], bh[c], acc[r][c], 0, 0, 0);
        }
    }
    __syncthreads();
  }
  #pragma unroll
  for (int rt = 0; rt < 4; rt++)
    #pragma unroll
    for (int ct = 0; ct < 4; ct++){
      int col = n0 + wc + ct*16 + lr;
      int rowb = m0 + wr + rt*16 + lg*4;
      #pragma unroll
      for (int r = 0; r < 4; r++)
        cstore(&C[(size_t)(rowb+r)*N + col], acc[rt][ct][r]);
    }
}

// =====================================================================
// K1: wave-per-row rmsnorm: emits hi/lo split of s and shifted rq; + lr
// 4 rows/block, no block barriers
// =====================================================================
__global__ __launch_bounds__(256) void k_store_norm(
    const float* __restrict__ seq, const float* __restrict__ wsn,
    const float* __restrict__ wrn, const float* __restrict__ wstep,
    unsigned short* __restrict__ s_hi, unsigned short* __restrict__ s_lo,
    unsigned short* __restrict__ rq_hi, unsigned short* __restrict__ rq_lo,
    float* __restrict__ lrp)
{
  int wid = threadIdx.x >> 6, lane = threadIdx.x & 63;
  int row = blockIdx.x * 4 + wid;
  int b = row >> 12, t = row & 4095;
  const float* x = seq + (size_t)row * DIM;
  float4 v0 = *(const float4*)&x[lane*4];
  float4 v1 = *(const float4*)&x[256 + lane*4];
  float xv[8] = {v0.x, v0.y, v0.z, v0.w, v1.x, v1.y, v1.z, v1.w};
  float ss = 0.f;
  #pragma unroll
  for (int j = 0; j < 8; j++) ss += xv[j]*xv[j];
  #pragma unroll
  for (int m = 1; m < 64; m <<= 1) ss += __shfl_xor(ss, m);
  float rinv = rsqrtf(ss * (1.f/DIM) + 1e-6f);

  float4 w0 = *(const float4*)&wsn[lane*4];
  float4 w1 = *(const float4*)&wsn[256 + lane*4];
  float wv[8] = {w0.x, w0.y, w0.z, w0.w, w1.x, w1.y, w1.z, w1.w};
  float sv[8];
  short4v h0, h1, l0, l1;
  #pragma unroll
  for (int j = 0; j < 8; j++){
    sv[j] = xv[j] * rinv * wv[j];
    unsigned short hi = f2b(sv[j]);
    unsigned short lo = f2b(sv[j] - b2f(hi));
    if (j < 4){ h0[j] = (short)hi; l0[j] = (short)lo; }
    else      { h1[j-4] = (short)hi; l1[j-4] = (short)lo; }
  }
  size_t sbase = (size_t)row*DIM + lane*4;
  *(short4v*)&s_hi[sbase] = h0; *(short4v*)&s_hi[sbase + 256] = h1;
  *(short4v*)&s_lo[sbase] = l0; *(short4v*)&s_lo[sbase + 256] = l1;

  if (t >= CH){
    float4 r0 = *(const float4*)&wrn[lane*4];
    float4 r1 = *(const float4*)&wrn[256 + lane*4];
    float rv[8] = {r0.x, r0.y, r0.z, r0.w, r1.x, r1.y, r1.z, r1.w};
    short4v rh0, rh1, rl0, rl1;
    #pragma unroll
    for (int j = 0; j < 8; j++){
      float q = xv[j] * rinv * rv[j];
      unsigned short hi = f2b(q);
      unsigned short lo = f2b(q - b2f(hi));
      if (j < 4){ rh0[j] = (short)hi; rl0[j] = (short)lo; }
      else      { rh1[j-4] = (short)hi; rl1[j-4] = (short)lo; }
    }
    size_t rbase = ((size_t)b*SEQ + (t - CH))*DIM + lane*4;
    *(short4v*)&rq_hi[rbase] = rh0; *(short4v*)&rq_hi[rbase + 256] = rh1;
    *(short4v*)&rq_lo[rbase] = rl0; *(short4v*)&rq_lo[rbase + 256] = rl1;
  }

  // lr: dot(s_row, w_step[:,h]) for h=0..7
  float acc[8] = {0.f,0.f,0.f,0.f,0.f,0.f,0.f,0.f};
  #pragma unroll
  for (int j = 0; j < 8; j++){
    int e = (j < 4) ? (lane*4 + j) : (256 + lane*4 + (j-4));
    float4 wa = *(const float4*)&wstep[e*8];
    float4 wb = *(const float4*)&wstep[e*8 + 4];
    acc[0] += sv[j]*wa.x; acc[1] += sv[j]*wa.y; acc[2] += sv[j]*wa.z; acc[3] += sv[j]*wa.w;
    acc[4] += sv[j]*wb.x; acc[5] += sv[j]*wb.y; acc[6] += sv[j]*wb.z; acc[7] += sv[j]*wb.w;
  }
  #pragma unroll
  for (int m = 1; m < 64; m <<= 1){
    #pragma unroll
    for (int h = 0; h < 8; h++) acc[h] += __shfl_xor(acc[h], m);
  }
  float a = acc[0];
  #pragma unroll
  for (int h = 1; h < 8; h++) a = (lane == h) ? acc[h] : a;
  if (lane < 8)
    lrp[(size_t)row*HEADS + lane] = __expf(-15.f * sigmoidf_(a));
}

// =====================================================================
// K3: chunk stats (reads hi+lo s)
// =====================================================================
__global__ __launch_bounds__(256) void k_stats(
    const unsigned short* __restrict__ s_hi, const unsigned short* __restrict__ s_lo,
    const float* __restrict__ lrp,
    const float* __restrict__ wmom, const float* __restrict__ wdec,
    float* __restrict__ mg, float* __restrict__ dec, float* __restrict__ lrc)
{
  __shared__ float smean[DIM];
  int blk = blockIdx.x;
  int b = blk >> 6, ch = blk & 63;
  int tid = threadIdx.x;
  size_t off = ((size_t)(b*SEQ + ch*CH)) * DIM;
  for (int e = tid; e < DIM; e += 256){
    float acc = 0.f;
    for (int i = 0; i < CH; i++)
      acc += b2f(s_hi[off + (size_t)i*DIM + e]) + b2f(s_lo[off + (size_t)i*DIM + e]);
    smean[e] = acc * (1.f/CH);
  }
  __syncthreads();
  int gh = tid >> 5, l = tid & 31;
  float am = 0.f, ad = 0.f;
  for (int e = l; e < DIM; e += 32){
    float v = smean[e];
    am += v * wmom[e*HEADS + gh];
    ad += v * wdec[e*HEADS + gh];
  }
  const float* lrbase = lrp + ((size_t)(b*SEQ + ch*CH)) * HEADS + gh;
  float al = lrbase[(size_t)l*HEADS] + lrbase[(size_t)(l+32)*HEADS];
  #pragma unroll
  for (int m = 1; m < 32; m <<= 1){
    am += __shfl_xor(am, m);
    ad += __shfl_xor(ad, m);
    al += __shfl_xor(al, m);
  }
  if (l == 0){
    int o = (b*HEADS + gh)*NC + ch;
    mg[o]  = sigmoidf_(am);
    dec[o] = sigmoidf_(ad);
    lrc[o] = al * (1.f/CH);
  }
}

// =====================================================================
// K4: per-chunk attention fwd+bwd (8 waves, 10 barriers, 127.5KB LDS)
// =====================================================================
__global__ __launch_bounds__(512) void k_grads(
    const float* __restrict__ kv,
    const float* __restrict__ wq, const float* __restrict__ wk,
    const float* __restrict__ wv1, const float* __restrict__ wv2,
    const float* __restrict__ lrc, float* __restrict__ g)
{
  __shared__ __align__(16) unsigned short sm[12*TS];
  __shared__ __align__(16) float SC[64*66];
  unsigned short *Xr = sm,        *XT = sm + TS,
                 *s2 = sm + 2*TS, *s3 = sm + 3*TS, *s4 = sm + 4*TS,
                 *s5 = sm + 5*TS, *s6 = sm + 6*TS, *s7 = sm + 7*TS,
                 *s8 = sm + 8*TS, *s9 = sm + 9*TS, *s10 = sm + 10*TS,
                 *s11 = sm + 11*TS;
  unsigned short *SCu = (unsigned short*)SC;
  int chunk = blockIdx.x;
  int bh = chunk >> 6, t = chunk & 63;
  int b = bh >> 3, h = bh & 7;
  int tid = threadIdx.x;
  MM M = mmctx();
  const float* xbase = kv + ((size_t)(b*SEQ + t*CH)) * (2*DI) + h*DH;
  const float* tbase = xbase + DI;
  float negLr = -lrc[bh*NC + t];
  f32x4 acc[2], accV[2];

  // P0: loads. slots: Xr=X, XT=X^T, s2=WqT, s3=WkT, s4=Wv1T, s5=Wv2T, s6=Wv2row
  loadTile<true,true>(Xr, XT, xbase, 2*DI, tid);
  loadTile<false,true>(nullptr, s2, wq, 64, tid);
  loadTile<false,true>(nullptr, s3, wk, 64, tid);
  loadTile<false,true>(nullptr, s4, wv1, 64, tid);
  loadTile<true,true>(s6, s5, wv2, 64, tid);
  __syncthreads();
  // P1: Q->s7,s8T; K->s9,s10T; V->s11 row (hold acc for VT)
  mm64<false>(Xr, s2, acc, M);
  storeN64(s7, acc, M, 1.f); storeT64(s8, acc, M, 1.f);
  mm64<false>(Xr, s3, acc, M);
  storeN64(s9, acc, M, 1.f); storeT64(s10, acc, M, 1.f);
  mm64<false>(Xr, s4, accV, M);
  storeN64(s11, accV, M, 1.f);
  __syncthreads();
  // P2: VT->s2 (WqT dead); S = Q K^T /8 -> SC
  storeT64(s2, accV, M, 1.f);
  mm64<false>(s7, s9, acc, M);
  storeSC(SC, acc, M, 0.125f);
  __syncthreads();
  // P3: causal softmax -> Arow(s7), AT(s9)
  {
    int row = tid >> 3, q = tid & 7;
    float p[8];
    float mx = -1e30f;
    #pragma unroll
    for (int cc = 0; cc < 8; cc++){
      int col = q*8 + cc;
      float x = SC[row*66 + col];
      p[cc] = (col <= row) ? x : -1e9f;
      mx = fmaxf(mx, p[cc]);
    }
    mx = fmaxf(mx, __shfl_xor(mx, 1));
    mx = fmaxf(mx, __shfl_xor(mx, 2));
    mx = fmaxf(mx, __shfl_xor(mx, 4));
    float sum = 0.f;
    #pragma unroll
    for (int cc = 0; cc < 8; cc++){ p[cc] = __expf(p[cc] - mx); sum += p[cc]; }
    sum += __shfl_xor(sum, 1);
    sum += __shfl_xor(sum, 2);
    sum += __shfl_xor(sum, 4);
    float inv = 1.f / sum;
    #pragma unroll
    for (int cc = 0; cc < 8; cc++){
      int col = q*8 + cc;
      unsigned short hh = f2b(p[cc] * inv);
      s7[row*72 + col] = hh;
      s9[col*72 + row] = hh;
    }
  }
  __syncthreads();
  // P4: H = A @ V -> rawH(s3), rawHT(s4)
  mm64<false>(s7, s2, acc, M);
  storeN64(s3, acc, M, 1.f); storeT64(s4, acc, M, 1.f);
  __syncthreads();
  // P5: pred = silu(H)@Wv2T; T2 = (pred-tgt)*2/64 -> Xr(row), s2(T)
  mm64<true>(s3, s5, acc, M);
  #pragma unroll
  for (int ct = 0; ct < 2; ct++){
    int c  = M.colbase + ct*16 + M.lr;
    int mb = M.rowbase + M.lg*4;
    #pragma unroll
    for (int r = 0; r < 4; r++){
      float t2 = (acc[ct][r] - tbase[(size_t)(mb+r)*(2*DI) + c]) * (2.f/64.f);
      unsigned short hh = f2b(t2);
      Xr[(mb+r)*72 + c] = hh;
      s2[c*72 + (mb+r)] = hh;
    }
  }
  __syncthreads();
  // P6: dWv2 = silu(H)^T @ T2 -> g3; dHd = (T2@Wv2row)*dsilu(rawH) -> s5(row), SCu(T)
  mm64<true>(s4, s2, acc, M);
  storeG64(g + ((size_t)(3*NCHUNK + chunk))*4096, acc, M, negLr);
  mm64<false>(Xr, s6, acc, M);
  #pragma unroll
  for (int ct = 0; ct < 2; ct++){
    int c  = M.colbase + ct*16 + M.lr;
    int mb = M.rowbase + M.lg*4;
    #pragma unroll
    for (int r = 0; r < 4; r++){
      float x = b2f(s3[(mb+r)*72 + c]);
      float d = acc[ct][r] * dsilu_f(x);
      unsigned short hh = f2b(d);
      s5[(mb+r)*72 + c] = hh;
      SCu[c*72 + (mb+r)] = hh;
    }
  }
  __syncthreads();
  // P7: dA = dHd @ V^T -> Xr; dv = A^T @ dHd -> dvT(s2)
  mm64<false>(s5, s11, acc, M);
  storeN64(Xr, acc, M, 1.f);
  mm64<false>(s9, SCu, acc, M);
  storeT64(s2, acc, M, 1.f);
  __syncthreads();
  // P8: softmax bwd -> T3row(s3), T3T(s6); dWv1 = X^T @ dvT -> g2
  {
    int row = tid >> 3, q = tid & 7;
    float da[8], a[8], rs = 0.f;
    #pragma unroll
    for (int cc = 0; cc < 8; cc++){
      int col = q*8 + cc;
      da[cc] = b2f(Xr[row*72 + col]);
      a[cc]  = b2f(s7[row*72 + col]);
      rs += da[cc]*a[cc];
    }
    rs += __shfl_xor(rs, 1);
    rs += __shfl_xor(rs, 2);
    rs += __shfl_xor(rs, 4);
    #pragma unroll
    for (int cc = 0; cc < 8; cc++){
      int col = q*8 + cc;
      unsigned short hh = f2b(a[cc] * (da[cc] - rs));
      s3[row*72 + col] = hh;
      s6[col*72 + row] = hh;
    }
  }
  mm64<false>(XT, s2, acc, M);
  storeG64(g + ((size_t)(2*NCHUNK + chunk))*4096, acc, M, negLr);
  __syncthreads();
  // P9: dq = T3 @ KT /8 -> dqT(Xr); dk = T3T @ QT /8 -> dkT(s2)
  mm64<false>(s3, s10, acc, M);
  storeT64(Xr, acc, M, 0.125f);
  mm64<false>(s6, s8, acc, M);
  storeT64(s2, acc, M, 0.125f);
  __syncthreads();
  // P10: dWq = XT @ dqT -> g0; dWk = XT @ dkT -> g1
  mm64<false>(XT, Xr, acc, M);
  storeG64(g + ((size_t)(0*NCHUNK + chunk))*4096, acc, M, negLr);
  mm64<false>(XT, s2, acc, M);
  storeG64(g + ((size_t)(1*NCHUNK + chunk))*4096, acc, M, negLr);
}

// =====================================================================
// K5: double associative scan; in-place g -> per-chunk weights
// =====================================================================
__global__ __launch_bounds__(256) void k_scan(
    float* __restrict__ g, const float* __restrict__ mg, const float* __restrict__ dec,
    const float* __restrict__ wq, const float* __restrict__ wk,
    const float* __restrict__ wv1, const float* __restrict__ wv2)
{
  int idx = blockIdx.x * 256 + threadIdx.x;
  int e = idx & 4095;
  int bh = (idx >> 12) & 15;
  int name = idx >> 16;
  const float* past = (name == 0) ? wq : (name == 1) ? wk : (name == 2) ? wv1 : wv2;
  float base = past[e];
  float m = 0.f, u = 0.f;
  for (int t = 0; t < NC; t++){
    size_t off = ((size_t)(name*NCHUNK + bh*NC + t)) * 4096 + e;
    float su = g[off];
    float gm = mg[bh*NC + t];
    float dc = dec[bh*NC + t];
    m = gm * m + su;
    u = (1.f - dc) * u + m;
    g[off] = base + u;
  }
}

// =====================================================================
// K6: retrieval attention (8 waves, 6 tiles + SC = 72KB -> 2 blk/CU)
// qb bf16 in; vals hi/lo bf16 out
// =====================================================================
__global__ __launch_bounds__(512, 4) void k_retrieve(
    const unsigned short* __restrict__ qb, const float* __restrict__ Wg,
    unsigned short* __restrict__ vals_hi, unsigned short* __restrict__ vals_lo)
{
  __shared__ __align__(16) unsigned short sm[6*TS];
  __shared__ __align__(16) float SC[64*66];
  unsigned short *Xr = sm,       *Wt = sm + TS,   *Qr = sm + 2*TS,
                 *Kr = sm + 3*TS, *Vt = sm + 4*TS, *Hr = sm + 5*TS;
  unsigned short *Ar = (unsigned short*)SC;
  int chunk = blockIdx.x;
  int bh = chunk >> 6, t = chunk & 63;
  int b = bh >> 3, h = bh & 7;
  int tid = threadIdx.x;
  MM M = mmctx();
  const unsigned short* xb = qb + ((size_t)(b*SEQ + t*CH)) * DI + h*DH;
  f32x4 acc[2];

  // P0: X, WqT
  loadTileBrow(Xr, xb, DI, tid);
  loadTile<false,true>(nullptr, Wt, Wg + ((size_t)(0*NCHUNK + chunk))*4096, 64, tid);
  __syncthreads();
  // P1: Q -> Qr; prefetch WkT -> Hr
  mm64<false>(Xr, Wt, acc, M); storeN64(Qr, acc, M, 1.f);
  loadTile<false,true>(nullptr, Hr, Wg + ((size_t)(1*NCHUNK + chunk))*4096, 64, tid);
  __syncthreads();
  // P2: K -> Kr; prefetch Wv1T -> Wt
  mm64<false>(Xr, Hr, acc, M); storeN64(Kr, acc, M, 1.f);
  loadTile<false,true>(nullptr, Wt, Wg + ((size_t)(2*NCHUNK + chunk))*4096, 64, tid);
  __syncthreads();
  // P3: V -> Vt(T); S = Q K^T /8 -> SC; prefetch Wv2T -> Hr
  mm64<false>(Xr, Wt, acc, M); storeT64(Vt, acc, M, 1.f);
  mm64<false>(Qr, Kr, acc, M); storeSC(SC, acc, M, 0.125f);
  loadTile<false,true>(nullptr, Hr, Wg + ((size_t)(3*NCHUNK + chunk))*4096, 64, tid);
  __syncthreads();
  // P4: causal softmax SC -> Ar (SC overlay)
  {
    int row = tid >> 3, q = tid & 7;
    float p[8];
    float mx = -1e30f;
    #pragma unroll
    for (int cc = 0; cc < 8; cc++){
      int col = q*8 + cc;
      float x = SC[row*66 + col];
      p[cc] = (col <= row) ? x : -1e9f;
      mx = fmaxf(mx, p[cc]);
    }
    mx = fmaxf(mx, __shfl_xor(mx, 1));
    mx = fmaxf(mx, __shfl_xor(mx, 2));
    mx = fmaxf(mx, __shfl_xor(mx, 4));
    float sum = 0.f;
    #pragma unroll
    for (int cc = 0; cc < 8; cc++){ p[cc] = __expf(p[cc] - mx); sum += p[cc]; }
    sum += __shfl_xor(sum, 1);
    sum += __shfl_xor(sum, 2);
    sum += __shfl_xor(sum, 4);
    float inv = 1.f / sum;
    __syncthreads();   // drain SC reads before overlay write
    #pragma unroll
    for (int cc = 0; cc < 8; cc++){
      int col = q*8 + cc;
      Ar[row*72 + col] = f2b(p[cc] * inv);
    }
  }
  __syncthreads();
  // P5: H = A @ V -> Kr (row)
  mm64<false>(Ar, Vt, acc, M); storeN64(Kr, acc, M, 1.f);
  __syncthreads();
  // P6: out = silu(H) @ Wv2T -> vals hi/lo
  mm64<true>(Kr, Hr, acc, M);
  #pragma unroll
  for (int ct = 0; ct < 2; ct++){
    int c  = M.colbase + ct*16 + M.lr;
    int mb = M.rowbase + M.lg*4;
    #pragma unroll
    for (int r = 0; r < 4; r++){
      size_t o = ((size_t)(b*SEQ + t*CH + mb + r))*DI + h*DH + c;
      float v = acc[ct][r];
      unsigned short hi = f2b(v);
      vals_hi[o] = hi;
      vals_lo[o] = f2b(v - b2f(hi));
    }
  }
}

// =====================================================================
// K8: final rmsnorm + shift (wave-per-row)
// =====================================================================
__global__ __launch_bounds__(256) void k_outnorm(
    const float* __restrict__ tmp, const float* __restrict__ wpn, float* __restrict__ out)
{
  int wid = threadIdx.x >> 6, lane = threadIdx.x & 63;
  int row = blockIdx.x * 4 + wid;          // 0..8063
  int b = row / (SEQ - CH), r = row % (SEQ - CH);
  const float* src = tmp + ((size_t)b*SEQ + r) * DIM;
  float* dst = out + ((size_t)b*SEQ + r + CH) * DIM;
  float4 v0 = *(const float4*)&src[lane*4];
  float4 v1 = *(const float4*)&src[256 + lane*4];
  float ss = v0.x*v0.x + v0.y*v0.y + v0.z*v0.z + v0.w*v0.w
           + v1.x*v1.x + v1.y*v1.y + v1.z*v1.z + v1.w*v1.w;
  #pragma unroll
  for (int m = 1; m < 64; m <<= 1) ss += __shfl_xor(ss, m);
  float rinv = rsqrtf(ss * (1.f/DIM) + 1e-6f);
  float4 w0 = *(const float4*)&wpn[lane*4];
  float4 w1 = *(const float4*)&wpn[256 + lane*4];
  float4 o0 = make_float4(v0.x*rinv*w0.x, v0.y*rinv*w0.y, v0.z*rinv*w0.z, v0.w*rinv*w0.w);
  float4 o1 = make_float4(v1.x*rinv*w1.x, v1.y*rinv*w1.y, v1.z*rinv*w1.z, v1.w*rinv*w1.w);
  *(float4*)&dst[lane*4] = o0;
  *(float4*)&dst[256 + lane*4] = o1;
}

// =====================================================================
extern "C" void kernel_launch(void* const* d_in, const int* in_sizes, int n_in,
                              void* d_out, int out_size, void* d_ws, size_t ws_size,
                              hipStream_t stream)
{
  (void)in_sizes; (void)n_in; (void)ws_size;
  const float* seq   = (const float*)d_in[0];
  const float* wsn   = (const float*)d_in[1];
  const float* wrn   = (const float*)d_in[2];
  const float* wpn   = (const float*)d_in[3];
  const float* w_q   = (const float*)d_in[4];
  const float* w_kv  = (const float*)d_in[5];
  const float* wstep = (const float*)d_in[6];
  const float* wmom  = (const float*)d_in[7];
  const float* wdec  = (const float*)d_in[8];
  const float* wcomb = (const float*)d_in[9];
  const float* wq    = (const float*)d_in[10];
  const float* wk    = (const float*)d_in[11];
  const float* wv1   = (const float*)d_in[12];
  const float* wv2   = (const float*)d_in[13];
  float* out = (float*)d_out;

  char* p = (char*)d_ws;
  unsigned short* s_hi  = (unsigned short*)p; p += (size_t)ROWS*DIM*2;
  unsigned short* s_lo  = (unsigned short*)p; p += (size_t)ROWS*DIM*2;
  unsigned short* rq_hi = (unsigned short*)p; p += (size_t)ROWS*DIM*2;
  unsigned short* rq_lo = (unsigned short*)p; p += (size_t)ROWS*DIM*2;
  float* kv             = (float*)p;          p += (size_t)ROWS*2*DI*4;
  unsigned short* qb    = (unsigned short*)p; p += (size_t)ROWS*DI*2;
  float* g              = (float*)p;          p += (size_t)4*NCHUNK*4096*4;
  float* lrp            = (float*)p;          p += (size_t)ROWS*HEADS*4;
  float* mg             = (float*)p;          p += (size_t)BH*NC*4;
  float* dec            = (float*)p;          p += (size_t)BH*NC*4;
  float* lrc            = (float*)p;          p += (size_t)BH*NC*4;
  unsigned short* wkvT_hi   = (unsigned short*)p; p += (size_t)(2*DI)*DIM*2;
  unsigned short* wkvT_lo   = (unsigned short*)p; p += (size_t)(2*DI)*DIM*2;
  unsigned short* wqT_hi    = (unsigned short*)p; p += (size_t)DI*DIM*2;
  unsigned short* wqT_lo    = (unsigned short*)p; p += (size_t)DI*DIM*2;
  unsigned short* wcombT_hi = (unsigned short*)p; p += (size_t)DIM*DI*2;
  unsigned short* wcombT_lo = (unsigned short*)p; p += (size_t)DIM*DI*2;
  // aliases over dead regions:
  float* tmp = (float*)s_hi;               // 16.8 MB (s dead after k_stats/kv-GEMM)
  unsigned short* vals_hi = rq_hi;         // rq dead after q-GEMM
  unsigned short* vals_lo = rq_lo;

  hipMemsetAsync(d_out, 0, (size_t)out_size * sizeof(float), stream);
  for (int b = 0; b < BATCH; b++){
    hipMemsetAsync(rq_hi + ((size_t)b*SEQ + (SEQ - CH))*DIM, 0, (size_t)CH*DIM*2, stream);
    hipMemsetAsync(rq_lo + ((size_t)b*SEQ + (SEQ - CH))*DIM, 0, (size_t)CH*DIM*2, stream);
  }

  // weight transposes+split ([N][K] bf16 hi/lo)
  k_wT<<<dim3((2*DI)/64, DIM/64), 256, 0, stream>>>(w_kv, wkvT_hi, wkvT_lo, DIM, 2*DI);
  k_wT<<<dim3(DI/64, DIM/64), 256, 0, stream>>>(w_q, wqT_hi, wqT_lo, DIM, DI);
  k_wT<<<dim3(DIM/64, DI/64), 256, 0, stream>>>(wcomb, wcombT_hi, wcombT_lo, DI, DIM);

  k_store_norm<<<ROWS/4, 256, 0, stream>>>(seq, wsn, wrn, wstep, s_hi, s_lo, rq_hi, rq_lo, lrp);
  k_gemm3<float><<<dim3((2*DI)/128, ROWS/128), 256, 0, stream>>>(
      s_hi, s_lo, wkvT_hi, wkvT_lo, kv, ROWS, 2*DI, DIM);
  k_stats<<<BATCH*NC, 256, 0, stream>>>(s_hi, s_lo, lrp, wmom, wdec, mg, dec, lrc);
  k_gemm3<unsigned short><<<dim3(DI/128, ROWS/128), 256, 0, stream>>>(
      rq_hi, rq_lo, wqT_hi, wqT_lo, qb, ROWS, DI, DIM);
  k_grads<<<NCHUNK, 512, 0, stream>>>(kv, wq, wk, wv1, wv2, lrc, g);
  k_scan<<<(4*BH*4096)/256, 256, 0, stream>>>(g, mg, dec, wq, wk, wv1, wv2);
  k_retrieve<<<NCHUNK, 512, 0, stream>>>(qb, g, vals_hi, vals_lo);
  k_gemm3<float><<<dim3(DIM/128, ROWS/128), 256, 0, stream>>>(
      vals_hi, vals_lo, wcombT_hi, wcombT_lo, tmp, ROWS, DIM, DI);
  k_outnorm<<<(BATCH*(SEQ - CH))/4, 256, 0, stream>>>(tmp, wpn, out);
}